// Round 17
// baseline (211.011 us; speedup 1.0000x reference)
//
#include <hip/hip_runtime.h>
#include <math.h>

#define EPSV 0.1f
#define MAX_ITER 10
constexpr int NB       = 16;
constexpr int IN_SIZE  = 1024;
constexpr int IN_DIM   = 1024;
constexpr int HEADS    = 4;
constexpr int OUT_SIZE = 128;
constexpr int OUT_DIM  = 1024;

typedef __attribute__((ext_vector_type(8))) _Float16 f16x8;
typedef __attribute__((ext_vector_type(4))) float f32x4;

__device__ __forceinline__ unsigned cvth2(float lo, float hi) {
    _Float16 a = (_Float16)lo, b = (_Float16)hi;
    unsigned short ua = *(unsigned short*)&a, ub = *(unsigned short*)&b;
    return (unsigned)ua | ((unsigned)ub << 16);
}
__device__ __forceinline__ unsigned short cvth1(float f) {
    _Float16 a = (_Float16)f;
    return *(unsigned short*)&a;
}
__device__ __forceinline__ unsigned short bf16rne(float f) {
    unsigned a = __float_as_uint(f);
    return (unsigned short)((a + 0x7fffu + ((a >> 16) & 1u)) >> 16);
}
// async global->LDS, 16 B per lane: HW writes lane l at ldsbase + l*16.
__device__ __forceinline__ void glds16(const void* g, void* l) {
    __builtin_amdgcn_global_load_lds(
        (const __attribute__((address_space(1))) unsigned int*)g,
        (__attribute__((address_space(3))) unsigned int*)l, 16, 0, 0);
}

// ---------------------------------------------------------------------------
// MFMA fp16 GEMM, M fixed 128, DOUBLE-BUFFERED 2-phase pipeline (T3-min):
// prologue stages buf0; each step issues glds for buf^1 BEFORE compute, one
// barrier per step drains the prefetch after MFMA has covered its latency.
// A fp16 glds (linear LDS [rows][32]); B fp16 glds or fp32 reg-staged.
// CMODE: 1 = fp16 store, 2 = f32+bias+relu, 4 = f32 raw (split-K partial)
// ---------------------------------------------------------------------------
template<bool B_F32, int CMODE, int NF, bool AKBLK, bool SWAP>
__global__ __launch_bounds__(256)
void mfma_gemm(const void* __restrict__ Ap, const void* __restrict__ Bp,
               const float* __restrict__ bias, void* __restrict__ Cp,
               int K, int lda, int ldb, int ldc, int div,
               long AsN, long AsM, long BsN, long BsM, long CsN, long CsM,
               long AkStride, float alpha)
{
    constexpr int BN   = NF * 32;
    constexpr int BSTR = B_F32 ? 40 : 32;   // B LDS row stride (elems)
    const int z  = SWAP ? blockIdx.x : blockIdx.z;
    const int n0 = (SWAP ? blockIdx.z : blockIdx.x) * BN;
    const long aoff = (long)(z / div) * AsN + (long)(z % div) * AsM;
    const long boff = (long)(z / div) * BsN + (long)(z % div) * BsM;
    const long coff = (long)(z / div) * CsN + (long)(z % div) * CsM;

    __shared__ short As[2][128 * 32];
    __shared__ short Bs[2][BN * BSTR];

    const int t = threadIdx.x;
    const int lane = t & 63;
    const int w = t >> 6, wr = w >> 1, wc = w & 1;
    const int lrow = lane >> 2, lce = (lane & 3) * 8;   // glds lane mapping

    auto stage = [&](int buf, int k0) {
        const long abase = AKBLK ? aoff + (long)(k0 >> 10) * AkStride + (k0 & 1023)
                                 : aoff + k0;
        const long bbase = boff + k0;
        #pragma unroll
        for (int j = 0; j < 2; ++j) {
            const int row0 = (w * 2 + j) * 16;
            glds16((const short*)Ap + abase + (long)(row0 + lrow) * lda + lce,
                   &As[buf][row0 * 32]);
        }
        if (B_F32) {
            #pragma unroll
            for (int itr = 0; itr < BN / 64; ++itr) {
                const int idx = itr * 256 + t;
                const int row = idx >> 2, kq = idx & 3;
                const float* s = (const float*)Bp + bbase + (long)(n0 + row) * ldb + kq * 8;
                const float4 f0 = *(const float4*)s, f1 = *(const float4*)(s + 4);
                uint4 p;
                p.x = cvth2(f0.x, f0.y); p.y = cvth2(f0.z, f0.w);
                p.z = cvth2(f1.x, f1.y); p.w = cvth2(f1.z, f1.w);
                *(uint4*)&Bs[buf][row * BSTR + kq * 8] = p;
            }
        } else {
            #pragma unroll
            for (int j = 0; j < BN / 64; ++j) {
                const int row0 = (w * (BN / 64) + j) * 16;
                glds16((const short*)Bp + bbase + (long)(n0 + row0 + lrow) * ldb + lce,
                       &Bs[buf][row0 * 32]);
            }
        }
    };

    f32x4 acc[4][NF];
    #pragma unroll
    for (int i = 0; i < 4; ++i)
        #pragma unroll
        for (int j = 0; j < NF; ++j) { acc[i][j].x = 0.f; acc[i][j].y = 0.f; acc[i][j].z = 0.f; acc[i][j].w = 0.f; }

    stage(0, 0);
    __syncthreads();
    int cur = 0;

    for (int k0 = 0; k0 < K; k0 += 32) {
        if (k0 + 32 < K) stage(cur ^ 1, k0 + 32);

        f16x8 af[4], bfr[NF];
        #pragma unroll
        for (int mi = 0; mi < 4; ++mi)
            af[mi] = *(const f16x8*)&As[cur][(wr * 64 + mi * 16 + (lane & 15)) * 32 + (lane >> 4) * 8];
        #pragma unroll
        for (int ni = 0; ni < NF; ++ni)
            bfr[ni] = *(const f16x8*)&Bs[cur][(wc * (BN / 2) + ni * 16 + (lane & 15)) * BSTR + (lane >> 4) * 8];
        #pragma unroll
        for (int mi = 0; mi < 4; ++mi)
            #pragma unroll
            for (int ni = 0; ni < NF; ++ni)
                acc[mi][ni] = __builtin_amdgcn_mfma_f32_16x16x32_f16(af[mi], bfr[ni], acc[mi][ni], 0, 0, 0);
        __syncthreads();
        cur ^= 1;
    }

    #pragma unroll
    for (int mi = 0; mi < 4; ++mi) {
        #pragma unroll
        for (int ni = 0; ni < NF; ++ni) {
            #pragma unroll
            for (int j = 0; j < 4; ++j) {
                const int row = wr * 64 + mi * 16 + (lane >> 4) * 4 + j;
                const int col = n0 + wc * (BN / 2) + ni * 16 + (lane & 15);
                float v = acc[mi][ni][j] * alpha;
                if (CMODE == 2) { v += bias[col]; v = fmaxf(v, 0.f); }
                if (CMODE == 2 || CMODE == 4) ((float*)Cp)[coff + (long)row * ldc + col] = v;
                else ((unsigned short*)Cp)[coff + (long)row * ldc + col] = cvth1(v);
            }
        }
    }
}

// ---------------------------------------------------------------------------
__global__ __launch_bounds__(256)
void splitk_reduce(const float* __restrict__ part, const float* __restrict__ bias,
                   float* __restrict__ out)
{
    const long idx = ((long)blockIdx.x * 256 + threadIdx.x) * 4;
    const int o = (int)(idx & 1023);
    const float4 p0 = *(const float4*)(part + idx);
    const float4 p1 = *(const float4*)(part + 2097152 + idx);
    const float4 p2 = *(const float4*)(part + 2 * 2097152 + idx);
    const float4 p3 = *(const float4*)(part + 3 * 2097152 + idx);
    const float4 bv = *(const float4*)(bias + o);
    float4 r;
    r.x = fmaxf(p0.x + p1.x + p2.x + p3.x + bv.x, 0.f);
    r.y = fmaxf(p0.y + p1.y + p2.y + p3.y + bv.y, 0.f);
    r.z = fmaxf(p0.z + p1.z + p2.z + p3.z + bv.z, 0.f);
    r.w = fmaxf(p0.w + p1.w + p2.w + p3.w + bv.w, 0.f);
    *(float4*)(out + idx) = r;
}

// ---------------------------------------------------------------------------
__global__ __launch_bounds__(256)
void cvt_f16(const float* __restrict__ in, unsigned short* __restrict__ out)
{
    const long i8 = ((long)blockIdx.x * 256 + threadIdx.x) * 8;
    const float4 f0 = *(const float4*)(in + i8), f1 = *(const float4*)(in + i8 + 4);
    uint4 p;
    p.x = cvth2(f0.x, f0.y); p.y = cvth2(f0.z, f0.w);
    p.z = cvth2(f1.x, f1.y); p.w = cvth2(f1.z, f1.w);
    *(uint4*)(out + i8) = p;
}

// ---------------------------------------------------------------------------
// GEMM1 fused, double-buffered glds both operands (fp16). Computes
// K = 10*otwH . xH^T per (b, 128-i chunk); colmax -> Mi; ek = bf16(exp).
// XCD-aligned: tile = blockIdx.x (grid 64,1,8).
// ---------------------------------------------------------------------------
__global__ __launch_bounds__(256)
void gemm1_exp(const unsigned short* __restrict__ otwH,
               const unsigned short* __restrict__ xH,
               unsigned short* __restrict__ ekb, float* __restrict__ MiB)
{
    const int zb = blockIdx.x;                // b = n*4+m  (XCD-aligned)
    const int nn = zb >> 2, mm = zb & 3;
    const unsigned short* A = otwH + (long)mm * (OUT_SIZE * IN_DIM);
    const unsigned short* B = xH + (long)nn * (IN_SIZE * IN_DIM);
    const int n0 = blockIdx.z * 128;          // i-chunk

    __shared__ short As[2][128 * 32];
    __shared__ short Bs[2][128 * 32];
    __shared__ float colmax[2][128];

    const int t = threadIdx.x;
    const int lane = t & 63;
    const int w = t >> 6, wr = w >> 1, wc = w & 1;
    const int lrow = lane >> 2, lce = (lane & 3) * 8;

    auto stage = [&](int buf, int k0) {
        #pragma unroll
        for (int j = 0; j < 2; ++j) {
            const int row0 = (w * 2 + j) * 16;
            glds16(A + (long)(row0 + lrow) * 1024 + k0 + lce, &As[buf][row0 * 32]);
        }
        #pragma unroll
        for (int j = 0; j < 2; ++j) {
            const int row0 = (w * 2 + j) * 16;
            glds16(B + (long)(n0 + row0 + lrow) * 1024 + k0 + lce, &Bs[buf][row0 * 32]);
        }
    };

    f32x4 acc[4][4];
    #pragma unroll
    for (int i = 0; i < 4; ++i)
        #pragma unroll
        for (int j = 0; j < 4; ++j) { acc[i][j].x = 0.f; acc[i][j].y = 0.f; acc[i][j].z = 0.f; acc[i][j].w = 0.f; }

    stage(0, 0);
    __syncthreads();
    int cur = 0;

    for (int k0 = 0; k0 < 1024; k0 += 32) {
        if (k0 + 32 < 1024) stage(cur ^ 1, k0 + 32);

        f16x8 af[4], bfr[4];
        #pragma unroll
        for (int mi = 0; mi < 4; ++mi)
            af[mi] = *(const f16x8*)&As[cur][(wr * 64 + mi * 16 + (lane & 15)) * 32 + (lane >> 4) * 8];
        #pragma unroll
        for (int ni = 0; ni < 4; ++ni)
            bfr[ni] = *(const f16x8*)&Bs[cur][(wc * 64 + ni * 16 + (lane & 15)) * 32 + (lane >> 4) * 8];
        #pragma unroll
        for (int mi = 0; mi < 4; ++mi)
            #pragma unroll
            for (int ni = 0; ni < 4; ++ni)
                acc[mi][ni] = __builtin_amdgcn_mfma_f32_16x16x32_f16(af[mi], bfr[ni], acc[mi][ni], 0, 0, 0);
        __syncthreads();
        cur ^= 1;
    }

    float lm[4];
    #pragma unroll
    for (int ni = 0; ni < 4; ++ni) {
        float mx = -INFINITY;
        #pragma unroll
        for (int mi = 0; mi < 4; ++mi)
            #pragma unroll
            for (int j = 0; j < 4; ++j) mx = fmaxf(mx, acc[mi][ni][j]);
        mx *= 10.0f;
        mx = fmaxf(mx, __shfl_xor(mx, 16, 64));
        mx = fmaxf(mx, __shfl_xor(mx, 32, 64));
        lm[ni] = mx;
    }
    if ((lane >> 4) == 0) {
        #pragma unroll
        for (int ni = 0; ni < 4; ++ni) colmax[wr][wc * 64 + ni * 16 + lane] = lm[ni];
    }
    __syncthreads();
    float cm[4];
    #pragma unroll
    for (int ni = 0; ni < 4; ++ni) {
        const int c = wc * 64 + ni * 16 + (lane & 15);
        cm[ni] = fmaxf(colmax[0][c], colmax[1][c]);
    }
    if (wr == 0 && (lane >> 4) == 0) {
        #pragma unroll
        for (int ni = 0; ni < 4; ++ni)
            MiB[(long)zb * 1024 + n0 + wc * 64 + ni * 16 + lane] = cm[ni];
    }
    unsigned short* ekz = ekb + (long)zb * (OUT_SIZE * IN_SIZE);
    #pragma unroll
    for (int mi = 0; mi < 4; ++mi) {
        #pragma unroll
        for (int ni = 0; ni < 4; ++ni) {
            const int col = n0 + wc * 64 + ni * 16 + (lane & 15);
            #pragma unroll
            for (int j = 0; j < 4; ++j) {
                const int row = wr * 64 + mi * 16 + (lane >> 4) * 4 + j;
                ekz[(long)row * 1024 + col] = bf16rne(__expf(fmaf(acc[mi][ni][j], 10.f, -cm[ni])));
            }
        }
    }
}

// ---------------------------------------------------------------------------
__global__ __launch_bounds__(256)
void transpose_cvt(const float* __restrict__ x, unsigned short* __restrict__ xT)
{
    const int n = blockIdx.z, i0 = blockIdx.y * 64, d0 = blockIdx.x * 64;
    const float* xs = x + (long)n * (IN_SIZE * IN_DIM);
    unsigned short* xo = xT + (long)n * (IN_SIZE * IN_DIM);
    __shared__ float tile[64][65];
    const int t = threadIdx.x;
    const int r = t >> 4, c4 = (t & 15) * 4;
    #pragma unroll
    for (int rr = 0; rr < 4; ++rr) {
        const float4 v = *(const float4*)(xs + (long)(i0 + rr * 16 + r) * IN_DIM + d0 + c4);
        *(float4*)&tile[rr * 16 + r][c4] = v;
    }
    __syncthreads();
    #pragma unroll
    for (int rr = 0; rr < 4; ++rr) {
        const int dl = rr * 16 + r;
        ushort4 o;
        o.x = cvth1(tile[c4 + 0][dl]); o.y = cvth1(tile[c4 + 1][dl]);
        o.z = cvth1(tile[c4 + 2][dl]); o.w = cvth1(tile[c4 + 3][dl]);
        *(ushort4*)(xo + (long)(d0 + dl) * IN_SIZE + i0 + c4) = o;
    }
}

// ---------------------------------------------------------------------------
// Sinkhorn v8: as v7 but combine + vmx + ev fused into one wave-0 phase
// (each lane owns 2 s-rows; in-wave butterfly gives the 128-max) ->
// 7 barriers/iter. Siblings co-located on XCD b%8 (grid 64x1x4).
// ---------------------------------------------------------------------------
__global__ __launch_bounds__(1024)
void sinkhorn_split(unsigned short* __restrict__ ekb,
                    const float* __restrict__ MiB,
                    float* __restrict__ xchg, unsigned int* __restrict__ ctr)
{
    const int b = blockIdx.x;          // tile 0..63 (XCD-aligned)
    const int q = blockIdx.z;          // i-quarter 0..3
    const int t = threadIdx.x;
    const int lane = t & 63, w = t >> 6;

    __shared__ unsigned ekw[128 * 129];
    __shared__ float part_u[8][256];
    __shared__ float part_v[8][128];
    __shared__ float eu_l[256];
    __shared__ float v_s[128], ev_s[128];
    __shared__ float red8[8];
    __shared__ float wg_s;

    {
        const unsigned short* src = ekb + (long)b * 131072 + q * 256;
        #pragma unroll
        for (int j = 0; j < 4; ++j) {
            const int idx = t + 1024 * j;
            const int s = idx >> 5, c8 = (idx & 31) * 8;
            const uint4 p = *(const uint4*)(src + (long)s * 1024 + c8);
            const int bd = s * 129 + (c8 >> 1);
            ekw[bd] = p.x; ekw[bd + 1] = p.y; ekw[bd + 2] = p.z; ekw[bd + 3] = p.w;
        }
    }
    float mi_t = 0.f, u_reg = 0.f, w_t = 0.f;
    if (t < 256) mi_t = MiB[(long)b * 1024 + q * 256 + t];
    if (t < 128) { v_s[t] = 0.f; ev_s[t] = 1.0f; }
    __syncthreads();

    const float A0 = -2.0794415416798357f;
    float vmx = 0.f;

    for (int it = 0; it < MAX_ITER; ++it) {
        // ---- u-pass partials ----
        {
            const int p = t & 127, sq = t >> 7;
            float s0 = 0.f, s1 = 0.f;
            #pragma unroll
            for (int j = 0; j < 16; ++j) {
                const int s = sq * 16 + j;
                const unsigned e = ekw[s * 129 + p];
                const float evv = ev_s[s];
                s0 = fmaf(__uint_as_float(e << 16),          evv, s0);
                s1 = fmaf(__uint_as_float(e & 0xffff0000u),  evv, s1);
            }
            part_u[sq][2 * p]     = s0;
            part_u[sq][2 * p + 1] = s1;
        }
        __syncthreads();                                   // C

        // ---- u update + wmx partials ----
        if (t < 256) {
            float S = part_u[0][t];
            #pragma unroll
            for (int g = 1; g < 8; ++g) S += part_u[g][t];
            const float un = A0 - u_reg - mi_t - vmx - __logf(S);
            u_reg = un;
            w_t = mi_t + un;
            float wl = w_t;
            #pragma unroll
            for (int m = 1; m < 64; m <<= 1) wl = fmaxf(wl, __shfl_xor(wl, m, 64));
            if (lane == 0) red8[4 + w] = wl;
        }
        __syncthreads();                                   // D
        const float wmx_l = fmaxf(fmaxf(red8[4], red8[5]), fmaxf(red8[6], red8[7]));
        if (t < 256) eu_l[t] = __expf(w_t - wmx_l);
        __syncthreads();                                   // E

        // ---- v-pass partials ----
        {
            const int s = t & 127, g = t >> 7;
            float acc = 0.f;
            #pragma unroll
            for (int j = 0; j < 16; ++j) {
                const int p = 16 * g + j;
                const unsigned e = ekw[s * 129 + p];
                const float2 eup = *(const float2*)&eu_l[2 * p];
                acc = fmaf(__uint_as_float(e << 16),         eup.x, acc);
                acc = fmaf(__uint_as_float(e & 0xffff0000u), eup.y, acc);
            }
            part_v[g][s] = acc;
        }
        __syncthreads();                                   // F

        // ---- publish, arrive, spin ----
        float* slot = xchg + ((long)(b * MAX_ITER + it) * 4 + q) * 160;
        if (t < 128) {
            float cp_l = part_v[0][t];
            #pragma unroll
            for (int g = 1; g < 8; ++g) cp_l += part_v[g][t];
            __hip_atomic_store(slot + t, cp_l, __ATOMIC_RELAXED, __HIP_MEMORY_SCOPE_AGENT);
        }
        if (t == 0)
            __hip_atomic_store(slot + 128, wmx_l, __ATOMIC_RELAXED, __HIP_MEMORY_SCOPE_AGENT);
        __syncthreads();                                   // G
        if (t == 0) {
            unsigned int* c = ctr + b * MAX_ITER + it;
            __hip_atomic_fetch_add(c, 1u, __ATOMIC_RELEASE, __HIP_MEMORY_SCOPE_AGENT);
            while (__hip_atomic_load(c, __ATOMIC_RELAXED, __HIP_MEMORY_SCOPE_AGENT) < 4u) {}
            (void)__hip_atomic_load(c, __ATOMIC_ACQUIRE, __HIP_MEMORY_SCOPE_AGENT);
        }
        __syncthreads();                                   // H

        // ---- combine + vmx + ev in wave 0 (2 s per lane) ----
        if (t < 64) {
            float* base = xchg + (long)(b * MAX_ITER + it) * 4 * 160;
            const float w0 = __hip_atomic_load(base + 0 * 160 + 128, __ATOMIC_RELAXED, __HIP_MEMORY_SCOPE_AGENT);
            const float w1 = __hip_atomic_load(base + 1 * 160 + 128, __ATOMIC_RELAXED, __HIP_MEMORY_SCOPE_AGENT);
            const float w2 = __hip_atomic_load(base + 2 * 160 + 128, __ATOMIC_RELAXED, __HIP_MEMORY_SCOPE_AGENT);
            const float w3 = __hip_atomic_load(base + 3 * 160 + 128, __ATOMIC_RELAXED, __HIP_MEMORY_SCOPE_AGENT);
            const float wg = fmaxf(fmaxf(w0, w1), fmaxf(w2, w3));
            const float e0 = __expf(w0 - wg), e1 = __expf(w1 - wg);
            const float e2 = __expf(w2 - wg), e3 = __expf(w3 - wg);
            float vn[2];
            #pragma unroll
            for (int h = 0; h < 2; ++h) {
                const int s = t + 64 * h;
                const float c0 = __hip_atomic_load(base + 0 * 160 + s, __ATOMIC_RELAXED, __HIP_MEMORY_SCOPE_AGENT);
                const float c1 = __hip_atomic_load(base + 1 * 160 + s, __ATOMIC_RELAXED, __HIP_MEMORY_SCOPE_AGENT);
                const float c2 = __hip_atomic_load(base + 2 * 160 + s, __ATOMIC_RELAXED, __HIP_MEMORY_SCOPE_AGENT);
                const float c3 = __hip_atomic_load(base + 3 * 160 + s, __ATOMIC_RELAXED, __HIP_MEMORY_SCOPE_AGENT);
                const float cp = c0 * e0 + c1 * e1 + c2 * e2 + c3 * e3;
                vn[h] = -v_s[s] - wg - __logf(cp);
                v_s[s] = vn[h];
            }
            if (t == 0) wg_s = wg;
            float xv = fmaxf(vn[0], vn[1]);
            #pragma unroll
            for (int m = 1; m < 64; m <<= 1) xv = fmaxf(xv, __shfl_xor(xv, m, 64));
            ev_s[t]      = __expf(vn[0] - xv);
            ev_s[t + 64] = __expf(vn[1] - xv);
            if (t == 0) red8[0] = xv;
        }
        __syncthreads();                                   // I
        vmx = red8[0];
    }

    // ---- write T fp16 over own ek slice ----
    const float wg = wg_s;
    if (t < 256) eu_l[t] = __expf(w_t - wg);
    if (t < 128) ev_s[t] = __expf(v_s[t] + wg);
    __syncthreads();
    unsigned short* To = ekb + (long)b * 131072 + q * 256;
    #pragma unroll
    for (int j = 0; j < 16; ++j) {
        const int idx = t + 1024 * j;
        const int s  = idx >> 7;
        const int ip = idx & 127;
        const unsigned e = ekw[s * 129 + ip];
        const float2 eup = *(const float2*)&eu_l[2 * ip];
        const float ec = ev_s[s];
        const float lo = __uint_as_float(e << 16)         * eup.x * ec;
        const float hi = __uint_as_float(e & 0xffff0000u) * eup.y * ec;
        *(unsigned*)(To + (long)s * 1024 + ip * 2) = cvth2(lo, hi);
    }
}

// ---------------------------------------------------------------------------
extern "C" void kernel_launch(void* const* d_in, const int* in_sizes, int n_in,
                              void* d_out, int out_size, void* d_ws, size_t ws_size,
                              hipStream_t stream)
{
    const float* x     = (const float*)d_in[0];   // [16][1024][1024]
    const float* otw   = (const float*)d_in[1];   // [4][128][1024]
    const float* lin_w = (const float*)d_in[2];   // [1024][4096]
    const float* lin_b = (const float*)d_in[3];   // [1024]
    float* out = (float*)d_out;                   // [16][128][1024] fp32 (8 MB)

    // ws (64 MB): [0,32M) = xH fp16 (gemm1) -> xT fp16 (GEMM2) -> partial f32
    //             [32M,48M) ek bf16 -> T fp16 in-place; [48M,64M) feat fp16
    unsigned short* xH   = (unsigned short*)d_ws;
    unsigned short* xT   = (unsigned short*)d_ws;
    unsigned short* ekb  = xH + 16777216;
    unsigned short* feat = ekb + 8388608;
    float* partial = (float*)d_ws;
    // d_out scratch (fully overwritten by splitk_reduce):
    //   Mi [64][1024] @0 ; xchg @131072 ; ctr @655360 ; otwH fp16 @786432
    float* MiB  = (float*)d_out;
    float* xchg = MiB + 131072;
    unsigned int* ctrB = (unsigned int*)(MiB + 655360);
    unsigned short* otwH = (unsigned short*)(MiB + 786432);

    hipMemsetAsync(ctrB, 0, 64 * MAX_ITER * sizeof(unsigned int), stream);

    // -1) otw -> fp16 ; x -> xH fp16 (linear)
    cvt_f16<<<dim3(256), 256, 0, stream>>>(otw, otwH);
    cvt_f16<<<dim3(8192), 256, 0, stream>>>(x, xH);

    // 1) fused K-GEMM + colmax + exp -> ek bf16, Mi (dbuf glds)
    gemm1_exp<<<dim3(64, 1, 8), 256, 0, stream>>>(otwH, xH, ekb, MiB);

    // 0') x -> xT fp16 over dead xH
    transpose_cvt<<<dim3(16, 16, NB), 256, 0, stream>>>(x, xT);

    // 2) Sinkhorn v8 -> T fp16 over ek
    sinkhorn_split<<<dim3(64, 1, 4), 1024, 0, stream>>>(ekb, MiB, xchg, ctrB);

    // 3) feat = T . xT^T (both fp16 glds dbuf, NF=4 grid (64,1,8))
    mfma_gemm<false, 1, 4, false, true><<<dim3(64, 1, 8), 256, 0, stream>>>(
        ekb, xT, nullptr, feat,
        1024, 1024, 1024, 1024, 4,
        524288, 131072, 1048576, 0, 524288, 131072, 0, 1.0f);

    // 4) split-K x4 GEMM3: A glds dbuf, B fp32 reg-staged
    mfma_gemm<true, 4, 2, false, false><<<dim3(16, 1, 64), 256, 0, stream>>>(
        feat, lin_w, nullptr, partial,
        1024, 1024, 4096, 1024, 16,
        131072, 524288, 1024, 0, 2097152, 131072, 0, 1.0f);

    // 5) out = relu(sum_ks partial + bias)
    splitk_reduce<<<dim3(2048), 256, 0, stream>>>(partial, lin_b, out);
}

// Round 18
// 204.952 us; speedup vs baseline: 1.0296x; 1.0296x over previous
//
#include <hip/hip_runtime.h>
#include <math.h>

#define EPSV 0.1f
#define MAX_ITER 10
constexpr int NB       = 16;
constexpr int IN_SIZE  = 1024;
constexpr int IN_DIM   = 1024;
constexpr int HEADS    = 4;
constexpr int OUT_SIZE = 128;
constexpr int OUT_DIM  = 1024;

typedef __attribute__((ext_vector_type(8))) _Float16 f16x8;
typedef __attribute__((ext_vector_type(4))) float f32x4;

__device__ __forceinline__ unsigned cvth2(float lo, float hi) {
    _Float16 a = (_Float16)lo, b = (_Float16)hi;
    unsigned short ua = *(unsigned short*)&a, ub = *(unsigned short*)&b;
    return (unsigned)ua | ((unsigned)ub << 16);
}
__device__ __forceinline__ unsigned short cvth1(float f) {
    _Float16 a = (_Float16)f;
    return *(unsigned short*)&a;
}
__device__ __forceinline__ unsigned short bf16rne(float f) {
    unsigned a = __float_as_uint(f);
    return (unsigned short)((a + 0x7fffu + ((a >> 16) & 1u)) >> 16);
}
// async global->LDS, 16 B per lane: HW writes lane l at ldsbase + l*16.
__device__ __forceinline__ void glds16(const void* g, void* l) {
    __builtin_amdgcn_global_load_lds(
        (const __attribute__((address_space(1))) unsigned int*)g,
        (__attribute__((address_space(3))) unsigned int*)l, 16, 0, 0);
}

// ---------------------------------------------------------------------------
// MFMA fp16 GEMM, M fixed 128, double-buffered. A fp16 glds (linear LDS
// [rows][32]); B fp16 glds or fp32 reg-staged (padded 40).
// CMODE: 1 = fp16 store, 2 = f32+bias+relu, 4 = f32 raw (split-K partial)
// ---------------------------------------------------------------------------
template<bool B_F32, int CMODE, int NF, bool AKBLK, bool SWAP>
__global__ __launch_bounds__(256)
void mfma_gemm(const void* __restrict__ Ap, const void* __restrict__ Bp,
               const float* __restrict__ bias, void* __restrict__ Cp,
               int K, int lda, int ldb, int ldc, int div,
               long AsN, long AsM, long BsN, long BsM, long CsN, long CsM,
               long AkStride, float alpha)
{
    constexpr int BN   = NF * 32;
    constexpr int BSTR = B_F32 ? 40 : 32;   // B LDS row stride (elems)
    const int z  = SWAP ? blockIdx.x : blockIdx.z;
    const int n0 = (SWAP ? blockIdx.z : blockIdx.x) * BN;
    const long aoff = (long)(z / div) * AsN + (long)(z % div) * AsM;
    const long boff = (long)(z / div) * BsN + (long)(z % div) * BsM;
    const long coff = (long)(z / div) * CsN + (long)(z % div) * CsM;

    __shared__ short As[2][128 * 32];
    __shared__ short Bs[2][BN * BSTR];

    const int t = threadIdx.x;
    const int lane = t & 63;
    const int w = t >> 6, wr = w >> 1, wc = w & 1;
    const int lrow = lane >> 2, lce = (lane & 3) * 8;   // glds lane mapping

    auto stage = [&](int buf, int k0) {
        const long abase = AKBLK ? aoff + (long)(k0 >> 10) * AkStride + (k0 & 1023)
                                 : aoff + k0;
        const long bbase = boff + k0;
        #pragma unroll
        for (int j = 0; j < 2; ++j) {
            const int row0 = (w * 2 + j) * 16;
            glds16((const short*)Ap + abase + (long)(row0 + lrow) * lda + lce,
                   &As[buf][row0 * 32]);
        }
        if (B_F32) {
            #pragma unroll
            for (int itr = 0; itr < BN / 64; ++itr) {
                const int idx = itr * 256 + t;
                const int row = idx >> 2, kq = idx & 3;
                const float* s = (const float*)Bp + bbase + (long)(n0 + row) * ldb + kq * 8;
                const float4 f0 = *(const float4*)s, f1 = *(const float4*)(s + 4);
                uint4 p;
                p.x = cvth2(f0.x, f0.y); p.y = cvth2(f0.z, f0.w);
                p.z = cvth2(f1.x, f1.y); p.w = cvth2(f1.z, f1.w);
                *(uint4*)&Bs[buf][row * BSTR + kq * 8] = p;
            }
        } else {
            #pragma unroll
            for (int j = 0; j < BN / 64; ++j) {
                const int row0 = (w * (BN / 64) + j) * 16;
                glds16((const short*)Bp + bbase + (long)(n0 + row0 + lrow) * ldb + lce,
                       &Bs[buf][row0 * 32]);
            }
        }
    };

    f32x4 acc[4][NF];
    #pragma unroll
    for (int i = 0; i < 4; ++i)
        #pragma unroll
        for (int j = 0; j < NF; ++j) { acc[i][j].x = 0.f; acc[i][j].y = 0.f; acc[i][j].z = 0.f; acc[i][j].w = 0.f; }

    stage(0, 0);
    __syncthreads();
    int cur = 0;

    for (int k0 = 0; k0 < K; k0 += 32) {
        if (k0 + 32 < K) stage(cur ^ 1, k0 + 32);

        f16x8 af[4], bfr[NF];
        #pragma unroll
        for (int mi = 0; mi < 4; ++mi)
            af[mi] = *(const f16x8*)&As[cur][(wr * 64 + mi * 16 + (lane & 15)) * 32 + (lane >> 4) * 8];
        #pragma unroll
        for (int ni = 0; ni < NF; ++ni)
            bfr[ni] = *(const f16x8*)&Bs[cur][(wc * (BN / 2) + ni * 16 + (lane & 15)) * BSTR + (lane >> 4) * 8];
        #pragma unroll
        for (int mi = 0; mi < 4; ++mi)
            #pragma unroll
            for (int ni = 0; ni < NF; ++ni)
                acc[mi][ni] = __builtin_amdgcn_mfma_f32_16x16x32_f16(af[mi], bfr[ni], acc[mi][ni], 0, 0, 0);
        __syncthreads();
        cur ^= 1;
    }

    #pragma unroll
    for (int mi = 0; mi < 4; ++mi) {
        #pragma unroll
        for (int ni = 0; ni < NF; ++ni) {
            #pragma unroll
            for (int j = 0; j < 4; ++j) {
                const int row = wr * 64 + mi * 16 + (lane >> 4) * 4 + j;
                const int col = n0 + wc * (BN / 2) + ni * 16 + (lane & 15);
                float v = acc[mi][ni][j] * alpha;
                if (CMODE == 2) { v += bias[col]; v = fmaxf(v, 0.f); }
                if (CMODE == 2 || CMODE == 4) ((float*)Cp)[coff + (long)row * ldc + col] = v;
                else ((unsigned short*)Cp)[coff + (long)row * ldc + col] = cvth1(v);
            }
        }
    }
}

// ---------------------------------------------------------------------------
__global__ __launch_bounds__(256)
void splitk_reduce(const float* __restrict__ part, const float* __restrict__ bias,
                   float* __restrict__ out)
{
    const long idx = ((long)blockIdx.x * 256 + threadIdx.x) * 4;
    const int o = (int)(idx & 1023);
    const float4 p0 = *(const float4*)(part + idx);
    const float4 p1 = *(const float4*)(part + 2097152 + idx);
    const float4 p2 = *(const float4*)(part + 2 * 2097152 + idx);
    const float4 p3 = *(const float4*)(part + 3 * 2097152 + idx);
    const float4 bv = *(const float4*)(bias + o);
    float4 r;
    r.x = fmaxf(p0.x + p1.x + p2.x + p3.x + bv.x, 0.f);
    r.y = fmaxf(p0.y + p1.y + p2.y + p3.y + bv.y, 0.f);
    r.z = fmaxf(p0.z + p1.z + p2.z + p3.z + bv.z, 0.f);
    r.w = fmaxf(p0.w + p1.w + p2.w + p3.w + bv.w, 0.f);
    *(float4*)(out + idx) = r;
}

// ---------------------------------------------------------------------------
__global__ __launch_bounds__(256)
void cvt_f16(const float* __restrict__ in, unsigned short* __restrict__ out)
{
    const long i8 = ((long)blockIdx.x * 256 + threadIdx.x) * 8;
    const float4 f0 = *(const float4*)(in + i8), f1 = *(const float4*)(in + i8 + 4);
    uint4 p;
    p.x = cvth2(f0.x, f0.y); p.y = cvth2(f0.z, f0.w);
    p.z = cvth2(f1.x, f1.y); p.w = cvth2(f1.z, f1.w);
    *(uint4*)(out + i8) = p;
}

// ---------------------------------------------------------------------------
// GEMM1 fused: A = otwH fp16 (glds, dbuf), B = x fp32 (reg-staged, dbuf).
// K = 10*otw.x^T per (b, 128-i chunk); colmax over all 128 s -> Mi;
// ek = bf16(exp(K-Mi)). XCD-aligned: tile = blockIdx.x (grid 64,1,8).
// ---------------------------------------------------------------------------
__global__ __launch_bounds__(256)
void gemm1_exp(const unsigned short* __restrict__ otwH, const float* __restrict__ x,
               unsigned short* __restrict__ ekb, float* __restrict__ MiB)
{
    const int zb = blockIdx.x;                // b = n*4+m  (XCD-aligned)
    const int nn = zb >> 2, mm = zb & 3;
    const unsigned short* A = otwH + (long)mm * (OUT_SIZE * IN_DIM);
    const float* B = x + (long)nn * (IN_SIZE * IN_DIM);
    const int n0 = blockIdx.z * 128;          // i-chunk

    __shared__ short As[2][128 * 32];
    __shared__ short Bs[2][128 * 40];
    __shared__ float colmax[2][128];

    const int t = threadIdx.x;
    const int lane = t & 63;
    const int w = t >> 6, wr = w >> 1, wc = w & 1;
    const int lrow = lane >> 2, lce = (lane & 3) * 8;

    auto stage = [&](int buf, int k0) {
        #pragma unroll
        for (int j = 0; j < 2; ++j) {
            const int row0 = (w * 2 + j) * 16;
            glds16(A + (long)(row0 + lrow) * 1024 + k0 + lce, &As[buf][row0 * 32]);
        }
        #pragma unroll
        for (int itr = 0; itr < 2; ++itr) {
            const int idx = itr * 256 + t;
            const int row = idx >> 2, kq = idx & 3;
            const float* s = B + (long)(n0 + row) * 1024 + k0 + kq * 8;
            const float4 f0 = *(const float4*)s, f1 = *(const float4*)(s + 4);
            uint4 p;
            p.x = cvth2(f0.x, f0.y); p.y = cvth2(f0.z, f0.w);
            p.z = cvth2(f1.x, f1.y); p.w = cvth2(f1.z, f1.w);
            *(uint4*)&Bs[buf][row * 40 + kq * 8] = p;
        }
    };

    f32x4 acc[4][4];
    #pragma unroll
    for (int i = 0; i < 4; ++i)
        #pragma unroll
        for (int j = 0; j < 4; ++j) { acc[i][j].x = 0.f; acc[i][j].y = 0.f; acc[i][j].z = 0.f; acc[i][j].w = 0.f; }

    stage(0, 0);
    __syncthreads();
    int cur = 0;

    for (int k0 = 0; k0 < 1024; k0 += 32) {
        if (k0 + 32 < 1024) stage(cur ^ 1, k0 + 32);

        f16x8 af[4], bfr[4];
        #pragma unroll
        for (int mi = 0; mi < 4; ++mi)
            af[mi] = *(const f16x8*)&As[cur][(wr * 64 + mi * 16 + (lane & 15)) * 32 + (lane >> 4) * 8];
        #pragma unroll
        for (int ni = 0; ni < 4; ++ni)
            bfr[ni] = *(const f16x8*)&Bs[cur][(wc * 64 + ni * 16 + (lane & 15)) * 40 + (lane >> 4) * 8];
        #pragma unroll
        for (int mi = 0; mi < 4; ++mi)
            #pragma unroll
            for (int ni = 0; ni < 4; ++ni)
                acc[mi][ni] = __builtin_amdgcn_mfma_f32_16x16x32_f16(af[mi], bfr[ni], acc[mi][ni], 0, 0, 0);
        __syncthreads();
        cur ^= 1;
    }

    float lm[4];
    #pragma unroll
    for (int ni = 0; ni < 4; ++ni) {
        float mx = -INFINITY;
        #pragma unroll
        for (int mi = 0; mi < 4; ++mi)
            #pragma unroll
            for (int j = 0; j < 4; ++j) mx = fmaxf(mx, acc[mi][ni][j]);
        mx *= 10.0f;
        mx = fmaxf(mx, __shfl_xor(mx, 16, 64));
        mx = fmaxf(mx, __shfl_xor(mx, 32, 64));
        lm[ni] = mx;
    }
    if ((lane >> 4) == 0) {
        #pragma unroll
        for (int ni = 0; ni < 4; ++ni) colmax[wr][wc * 64 + ni * 16 + lane] = lm[ni];
    }
    __syncthreads();
    float cm[4];
    #pragma unroll
    for (int ni = 0; ni < 4; ++ni) {
        const int c = wc * 64 + ni * 16 + (lane & 15);
        cm[ni] = fmaxf(colmax[0][c], colmax[1][c]);
    }
    if (wr == 0 && (lane >> 4) == 0) {
        #pragma unroll
        for (int ni = 0; ni < 4; ++ni)
            MiB[(long)zb * 1024 + n0 + wc * 64 + ni * 16 + lane] = cm[ni];
    }
    unsigned short* ekz = ekb + (long)zb * (OUT_SIZE * IN_SIZE);
    #pragma unroll
    for (int mi = 0; mi < 4; ++mi) {
        #pragma unroll
        for (int ni = 0; ni < 4; ++ni) {
            const int col = n0 + wc * 64 + ni * 16 + (lane & 15);
            #pragma unroll
            for (int j = 0; j < 4; ++j) {
                const int row = wr * 64 + mi * 16 + (lane >> 4) * 4 + j;
                ekz[(long)row * 1024 + col] = bf16rne(__expf(fmaf(acc[mi][ni][j], 10.f, -cm[ni])));
            }
        }
    }
}

// ---------------------------------------------------------------------------
__global__ __launch_bounds__(256)
void transpose_cvt(const float* __restrict__ x, unsigned short* __restrict__ xT)
{
    const int n = blockIdx.z, i0 = blockIdx.y * 64, d0 = blockIdx.x * 64;
    const float* xs = x + (long)n * (IN_SIZE * IN_DIM);
    unsigned short* xo = xT + (long)n * (IN_SIZE * IN_DIM);
    __shared__ float tile[64][65];
    const int t = threadIdx.x;
    const int r = t >> 4, c4 = (t & 15) * 4;
    #pragma unroll
    for (int rr = 0; rr < 4; ++rr) {
        const float4 v = *(const float4*)(xs + (long)(i0 + rr * 16 + r) * IN_DIM + d0 + c4);
        *(float4*)&tile[rr * 16 + r][c4] = v;
    }
    __syncthreads();
    #pragma unroll
    for (int rr = 0; rr < 4; ++rr) {
        const int dl = rr * 16 + r;
        ushort4 o;
        o.x = cvth1(tile[c4 + 0][dl]); o.y = cvth1(tile[c4 + 1][dl]);
        o.z = cvth1(tile[c4 + 2][dl]); o.w = cvth1(tile[c4 + 3][dl]);
        *(ushort4*)(xo + (long)(d0 + dl) * IN_SIZE + i0 + c4) = o;
    }
}

// ---------------------------------------------------------------------------
// Sinkhorn v7 (R15 version — fastest measured): 1024 threads, co-located
// siblings on XCD b%8 (grid 64x1x4), 8 barriers/iter, relaxed spin,
// writes T fp16 over the dead ek region.
// ---------------------------------------------------------------------------
__global__ __launch_bounds__(1024)
void sinkhorn_split(unsigned short* __restrict__ ekb,
                    const float* __restrict__ MiB,
                    float* __restrict__ xchg, unsigned int* __restrict__ ctr)
{
    const int b = blockIdx.x;          // tile 0..63 (XCD-aligned)
    const int q = blockIdx.z;          // i-quarter 0..3
    const int t = threadIdx.x;
    const int lane = t & 63, w = t >> 6;

    __shared__ unsigned ekw[128 * 129];
    __shared__ float part_u[8][256];
    __shared__ float part_v[8][128];
    __shared__ float eu_l[256];
    __shared__ float v_s[128], ev_s[128];
    __shared__ float red8[8];
    __shared__ float wg_s;

    {
        const unsigned short* src = ekb + (long)b * 131072 + q * 256;
        #pragma unroll
        for (int j = 0; j < 4; ++j) {
            const int idx = t + 1024 * j;
            const int s = idx >> 5, c8 = (idx & 31) * 8;
            const uint4 p = *(const uint4*)(src + (long)s * 1024 + c8);
            const int bd = s * 129 + (c8 >> 1);
            ekw[bd] = p.x; ekw[bd + 1] = p.y; ekw[bd + 2] = p.z; ekw[bd + 3] = p.w;
        }
    }
    float mi_t = 0.f, u_reg = 0.f, w_t = 0.f;
    if (t < 256) mi_t = MiB[(long)b * 1024 + q * 256 + t];
    if (t < 128) { v_s[t] = 0.f; ev_s[t] = 1.0f; }
    __syncthreads();

    const float A0 = -2.0794415416798357f;
    float vmx = 0.f;

    for (int it = 0; it < MAX_ITER; ++it) {
        {
            const int p = t & 127, sq = t >> 7;
            float s0 = 0.f, s1 = 0.f;
            #pragma unroll
            for (int j = 0; j < 16; ++j) {
                const int s = sq * 16 + j;
                const unsigned e = ekw[s * 129 + p];
                const float evv = ev_s[s];
                s0 = fmaf(__uint_as_float(e << 16),          evv, s0);
                s1 = fmaf(__uint_as_float(e & 0xffff0000u),  evv, s1);
            }
            part_u[sq][2 * p]     = s0;
            part_u[sq][2 * p + 1] = s1;
        }
        __syncthreads();

        if (t < 256) {
            float S = part_u[0][t];
            #pragma unroll
            for (int g = 1; g < 8; ++g) S += part_u[g][t];
            const float un = A0 - u_reg - mi_t - vmx - __logf(S);
            u_reg = un;
            w_t = mi_t + un;
            float wl = w_t;
            #pragma unroll
            for (int m = 1; m < 64; m <<= 1) wl = fmaxf(wl, __shfl_xor(wl, m, 64));
            if (lane == 0) red8[4 + w] = wl;
        }
        __syncthreads();
        const float wmx_l = fmaxf(fmaxf(red8[4], red8[5]), fmaxf(red8[6], red8[7]));
        if (t < 256) eu_l[t] = __expf(w_t - wmx_l);
        __syncthreads();

        {
            const int s = t & 127, g = t >> 7;
            float acc = 0.f;
            #pragma unroll
            for (int j = 0; j < 16; ++j) {
                const int p = 16 * g + j;
                const unsigned e = ekw[s * 129 + p];
                const float2 eup = *(const float2*)&eu_l[2 * p];
                acc = fmaf(__uint_as_float(e << 16),         eup.x, acc);
                acc = fmaf(__uint_as_float(e & 0xffff0000u), eup.y, acc);
            }
            part_v[g][s] = acc;
        }
        __syncthreads();

        float* slot = xchg + ((long)(b * MAX_ITER + it) * 4 + q) * 160;
        if (t < 128) {
            float cp_l = part_v[0][t];
            #pragma unroll
            for (int g = 1; g < 8; ++g) cp_l += part_v[g][t];
            __hip_atomic_store(slot + t, cp_l, __ATOMIC_RELAXED, __HIP_MEMORY_SCOPE_AGENT);
        }
        if (t == 0)
            __hip_atomic_store(slot + 128, wmx_l, __ATOMIC_RELAXED, __HIP_MEMORY_SCOPE_AGENT);
        __syncthreads();
        if (t == 0) {
            unsigned int* c = ctr + b * MAX_ITER + it;
            __hip_atomic_fetch_add(c, 1u, __ATOMIC_RELEASE, __HIP_MEMORY_SCOPE_AGENT);
            while (__hip_atomic_load(c, __ATOMIC_RELAXED, __HIP_MEMORY_SCOPE_AGENT) < 4u) {}
            (void)__hip_atomic_load(c, __ATOMIC_ACQUIRE, __HIP_MEMORY_SCOPE_AGENT);
        }
        __syncthreads();

        if (t < 128) {
            float* base = xchg + (long)(b * MAX_ITER + it) * 4 * 160;
            const float w0 = __hip_atomic_load(base + 0 * 160 + 128, __ATOMIC_RELAXED, __HIP_MEMORY_SCOPE_AGENT);
            const float w1 = __hip_atomic_load(base + 1 * 160 + 128, __ATOMIC_RELAXED, __HIP_MEMORY_SCOPE_AGENT);
            const float w2 = __hip_atomic_load(base + 2 * 160 + 128, __ATOMIC_RELAXED, __HIP_MEMORY_SCOPE_AGENT);
            const float w3 = __hip_atomic_load(base + 3 * 160 + 128, __ATOMIC_RELAXED, __HIP_MEMORY_SCOPE_AGENT);
            const float wg = fmaxf(fmaxf(w0, w1), fmaxf(w2, w3));
            const float c0 = __hip_atomic_load(base + 0 * 160 + t, __ATOMIC_RELAXED, __HIP_MEMORY_SCOPE_AGENT);
            const float c1 = __hip_atomic_load(base + 1 * 160 + t, __ATOMIC_RELAXED, __HIP_MEMORY_SCOPE_AGENT);
            const float c2 = __hip_atomic_load(base + 2 * 160 + t, __ATOMIC_RELAXED, __HIP_MEMORY_SCOPE_AGENT);
            const float c3 = __hip_atomic_load(base + 3 * 160 + t, __ATOMIC_RELAXED, __HIP_MEMORY_SCOPE_AGENT);
            const float cp = c0 * __expf(w0 - wg) + c1 * __expf(w1 - wg)
                           + c2 * __expf(w2 - wg) + c3 * __expf(w3 - wg);
            const float vn = -v_s[t] - wg - __logf(cp);
            v_s[t] = vn;
            if (t == 0) wg_s = wg;
            float xv = vn;
            #pragma unroll
            for (int m = 1; m < 64; m <<= 1) xv = fmaxf(xv, __shfl_xor(xv, m, 64));
            if (lane == 0) red8[w] = xv;
        }
        __syncthreads();
        vmx = fmaxf(red8[0], red8[1]);
        if (t < 128) ev_s[t] = __expf(v_s[t] - vmx);
        __syncthreads();
    }

    const float wg = wg_s;
    if (t < 256) eu_l[t] = __expf(w_t - wg);
    if (t < 128) ev_s[t] = __expf(v_s[t] + wg);
    __syncthreads();
    unsigned short* To = ekb + (long)b * 131072 + q * 256;
    #pragma unroll
    for (int j = 0; j < 16; ++j) {
        const int idx = t + 1024 * j;
        const int s  = idx >> 7;
        const int ip = idx & 127;
        const unsigned e = ekw[s * 129 + ip];
        const float2 eup = *(const float2*)&eu_l[2 * ip];
        const float ec = ev_s[s];
        const float lo = __uint_as_float(e << 16)         * eup.x * ec;
        const float hi = __uint_as_float(e & 0xffff0000u) * eup.y * ec;
        *(unsigned*)(To + (long)s * 1024 + ip * 2) = cvth2(lo, hi);
    }
}

// ---------------------------------------------------------------------------
extern "C" void kernel_launch(void* const* d_in, const int* in_sizes, int n_in,
                              void* d_out, int out_size, void* d_ws, size_t ws_size,
                              hipStream_t stream)
{
    const float* x     = (const float*)d_in[0];   // [16][1024][1024]
    const float* otw   = (const float*)d_in[1];   // [4][128][1024]
    const float* lin_w = (const float*)d_in[2];   // [1024][4096]
    const float* lin_b = (const float*)d_in[3];   // [1024]
    float* out = (float*)d_out;                   // [16][128][1024] fp32 (8 MB)

    // ws (64 MB): [0,32M) xT fp16 (dead after GEMM2 -> split-K partials)
    //             [32M,48M) ek bf16 -> T fp16 in-place; [48M,64M) feat fp16
    unsigned short* xT   = (unsigned short*)d_ws;
    unsigned short* ekb  = xT + 16777216;
    unsigned short* feat = ekb + 8388608;
    float* partial = (float*)d_ws;
    // d_out scratch (fully overwritten by splitk_reduce):
    //   Mi [64][1024] @0 ; xchg @131072 ; ctr @655360 ; otwH fp16 @786432
    float* MiB  = (float*)d_out;
    float* xchg = MiB + 131072;
    unsigned int* ctrB = (unsigned int*)(MiB + 655360);
    unsigned short* otwH = (unsigned short*)(MiB + 786432);

    hipMemsetAsync(ctrB, 0, 64 * MAX_ITER * sizeof(unsigned int), stream);

    // -1) otw -> fp16 (tiny)
    cvt_f16<<<dim3(256), 256, 0, stream>>>(otw, otwH);

    // 1) fused K-GEMM + colmax + exp: A otwH fp16 glds, B x fp32 reg-staged
    gemm1_exp<<<dim3(64, 1, 8), 256, 0, stream>>>(otwH, x, ekb, MiB);

    // 0) x -> xT fp16
    transpose_cvt<<<dim3(16, 16, NB), 256, 0, stream>>>(x, xT);

    // 2) Sinkhorn v7 -> T fp16 over ek
    sinkhorn_split<<<dim3(64, 1, 4), 1024, 0, stream>>>(ekb, MiB, xchg, ctrB);

    // 3) feat = T . xT^T (both fp16 glds dbuf, NF=4 grid (64,1,8))
    mfma_gemm<false, 1, 4, false, true><<<dim3(64, 1, 8), 256, 0, stream>>>(
        ekb, xT, nullptr, feat,
        1024, 1024, 1024, 1024, 4,
        524288, 131072, 1048576, 0, 524288, 131072, 0, 1.0f);

    // 4) split-K x4 GEMM3: A glds dbuf, B fp32 reg-staged
    mfma_gemm<true, 4, 2, false, false><<<dim3(16, 1, 64), 256, 0, stream>>>(
        feat, lin_w, nullptr, partial,
        1024, 1024, 4096, 1024, 16,
        131072, 524288, 1024, 0, 2097152, 131072, 0, 1.0f);

    // 5) out = relu(sum_ks partial + bias)
    splitk_reduce<<<dim3(2048), 256, 0, stream>>>(partial, lin_b, out);
}

// Round 19
// 191.394 us; speedup vs baseline: 1.1025x; 1.0708x over previous
//
#include <hip/hip_runtime.h>
#include <math.h>

#define EPSV 0.1f
#define MAX_ITER 10
constexpr int NB       = 16;
constexpr int IN_SIZE  = 1024;
constexpr int IN_DIM   = 1024;
constexpr int HEADS    = 4;
constexpr int OUT_SIZE = 128;
constexpr int OUT_DIM  = 1024;

typedef __attribute__((ext_vector_type(8))) _Float16 f16x8;
typedef __attribute__((ext_vector_type(4))) float f32x4;

__device__ __forceinline__ unsigned cvth2(float lo, float hi) {
    _Float16 a = (_Float16)lo, b = (_Float16)hi;
    unsigned short ua = *(unsigned short*)&a, ub = *(unsigned short*)&b;
    return (unsigned)ua | ((unsigned)ub << 16);
}
__device__ __forceinline__ unsigned short cvth1(float f) {
    _Float16 a = (_Float16)f;
    return *(unsigned short*)&a;
}
__device__ __forceinline__ unsigned short bf16rne(float f) {
    unsigned a = __float_as_uint(f);
    return (unsigned short)((a + 0x7fffu + ((a >> 16) & 1u)) >> 16);
}
// async global->LDS, 16 B per lane: HW writes lane l at ldsbase + l*16.
__device__ __forceinline__ void glds16(const void* g, void* l) {
    __builtin_amdgcn_global_load_lds(
        (const __attribute__((address_space(1))) unsigned int*)g,
        (__attribute__((address_space(3))) unsigned int*)l, 16, 0, 0);
}

// ---------------------------------------------------------------------------
// MFMA fp16 GEMM, M fixed 128, double-buffered. A fp16 glds (linear LDS
// [rows][32]); B fp16 glds or fp32 reg-staged (padded 40).
// CMODE: 1 = fp16 store, 2 = f32+bias+relu, 4 = f32 raw (split-K partial)
// HMAP : head-major tile remap: z=blockIdx.x, n=z&15, m=z>>4, b=n*4+m.
//        XCD = z%8 = n%8 -> all 4 heads of batch n co-resident on one XCD,
//        so the shared B slab (x / xT) is fetched from HBM ONCE per XCD
//        (intra-kernel L2 sharing; cross-kernel reuse is dead per R9/R10).
//        aoff = b*AsM, boff = n*BsN, coff = b*CsM.
// ---------------------------------------------------------------------------
template<bool B_F32, int CMODE, int NF, bool SWAP, bool HMAP>
__global__ __launch_bounds__(256)
void mfma_gemm(const void* __restrict__ Ap, const void* __restrict__ Bp,
               const float* __restrict__ bias, void* __restrict__ Cp,
               int K, int lda, int ldb, int ldc, int div,
               long AsN, long AsM, long BsN, long BsM, long CsN, long CsM,
               float alpha)
{
    constexpr int BN   = NF * 32;
    constexpr int BSTR = B_F32 ? 40 : 32;   // B LDS row stride (elems)
    const int z  = SWAP ? blockIdx.x : blockIdx.z;
    const int n0 = (SWAP ? blockIdx.z : blockIdx.x) * BN;
    long aoff, boff, coff;
    if (HMAP) {
        const int nn = z & 15, mm = z >> 4, bt = nn * 4 + mm;
        aoff = (long)bt * AsM; boff = (long)nn * BsN; coff = (long)bt * CsM;
    } else {
        aoff = (long)(z / div) * AsN + (long)(z % div) * AsM;
        boff = (long)(z / div) * BsN + (long)(z % div) * BsM;
        coff = (long)(z / div) * CsN + (long)(z % div) * CsM;
    }

    __shared__ short As[2][128 * 32];
    __shared__ short Bs[2][BN * BSTR];

    const int t = threadIdx.x;
    const int lane = t & 63;
    const int w = t >> 6, wr = w >> 1, wc = w & 1;
    const int lrow = lane >> 2, lce = (lane & 3) * 8;   // glds lane mapping

    auto stage = [&](int buf, int k0) {
        const long abase = aoff + k0;
        const long bbase = boff + k0;
        #pragma unroll
        for (int j = 0; j < 2; ++j) {
            const int row0 = (w * 2 + j) * 16;
            glds16((const short*)Ap + abase + (long)(row0 + lrow) * lda + lce,
                   &As[buf][row0 * 32]);
        }
        if (B_F32) {
            #pragma unroll
            for (int itr = 0; itr < BN / 64; ++itr) {
                const int idx = itr * 256 + t;
                const int row = idx >> 2, kq = idx & 3;
                const float* s = (const float*)Bp + bbase + (long)(n0 + row) * ldb + kq * 8;
                const float4 f0 = *(const float4*)s, f1 = *(const float4*)(s + 4);
                uint4 p;
                p.x = cvth2(f0.x, f0.y); p.y = cvth2(f0.z, f0.w);
                p.z = cvth2(f1.x, f1.y); p.w = cvth2(f1.z, f1.w);
                *(uint4*)&Bs[buf][row * BSTR + kq * 8] = p;
            }
        } else {
            #pragma unroll
            for (int j = 0; j < BN / 64; ++j) {
                const int row0 = (w * (BN / 64) + j) * 16;
                glds16((const short*)Bp + bbase + (long)(n0 + row0 + lrow) * ldb + lce,
                       &Bs[buf][row0 * 32]);
            }
        }
    };

    f32x4 acc[4][NF];
    #pragma unroll
    for (int i = 0; i < 4; ++i)
        #pragma unroll
        for (int j = 0; j < NF; ++j) { acc[i][j].x = 0.f; acc[i][j].y = 0.f; acc[i][j].z = 0.f; acc[i][j].w = 0.f; }

    stage(0, 0);
    __syncthreads();
    int cur = 0;

    for (int k0 = 0; k0 < K; k0 += 32) {
        if (k0 + 32 < K) stage(cur ^ 1, k0 + 32);

        f16x8 af[4], bfr[NF];
        #pragma unroll
        for (int mi = 0; mi < 4; ++mi)
            af[mi] = *(const f16x8*)&As[cur][(wr * 64 + mi * 16 + (lane & 15)) * 32 + (lane >> 4) * 8];
        #pragma unroll
        for (int ni = 0; ni < NF; ++ni)
            bfr[ni] = *(const f16x8*)&Bs[cur][(wc * (BN / 2) + ni * 16 + (lane & 15)) * BSTR + (lane >> 4) * 8];
        #pragma unroll
        for (int mi = 0; mi < 4; ++mi)
            #pragma unroll
            for (int ni = 0; ni < NF; ++ni)
                acc[mi][ni] = __builtin_amdgcn_mfma_f32_16x16x32_f16(af[mi], bfr[ni], acc[mi][ni], 0, 0, 0);
        __syncthreads();
        cur ^= 1;
    }

    #pragma unroll
    for (int mi = 0; mi < 4; ++mi) {
        #pragma unroll
        for (int ni = 0; ni < NF; ++ni) {
            #pragma unroll
            for (int j = 0; j < 4; ++j) {
                const int row = wr * 64 + mi * 16 + (lane >> 4) * 4 + j;
                const int col = n0 + wc * (BN / 2) + ni * 16 + (lane & 15);
                float v = acc[mi][ni][j] * alpha;
                if (CMODE == 2) { v += bias[col]; v = fmaxf(v, 0.f); }
                if (CMODE == 2 || CMODE == 4) ((float*)Cp)[coff + (long)row * ldc + col] = v;
                else ((unsigned short*)Cp)[coff + (long)row * ldc + col] = cvth1(v);
            }
        }
    }
}

// ---------------------------------------------------------------------------
__global__ __launch_bounds__(256)
void splitk_reduce(const float* __restrict__ part, const float* __restrict__ bias,
                   float* __restrict__ out)
{
    const long idx = ((long)blockIdx.x * 256 + threadIdx.x) * 4;
    const int o = (int)(idx & 1023);
    const float4 p0 = *(const float4*)(part + idx);
    const float4 p1 = *(const float4*)(part + 2097152 + idx);
    const float4 p2 = *(const float4*)(part + 2 * 2097152 + idx);
    const float4 p3 = *(const float4*)(part + 3 * 2097152 + idx);
    const float4 bv = *(const float4*)(bias + o);
    float4 r;
    r.x = fmaxf(p0.x + p1.x + p2.x + p3.x + bv.x, 0.f);
    r.y = fmaxf(p0.y + p1.y + p2.y + p3.y + bv.y, 0.f);
    r.z = fmaxf(p0.z + p1.z + p2.z + p3.z + bv.z, 0.f);
    r.w = fmaxf(p0.w + p1.w + p2.w + p3.w + bv.w, 0.f);
    *(float4*)(out + idx) = r;
}

// ---------------------------------------------------------------------------
__global__ __launch_bounds__(256)
void cvt_f16(const float* __restrict__ in, unsigned short* __restrict__ out)
{
    const long i8 = ((long)blockIdx.x * 256 + threadIdx.x) * 8;
    const float4 f0 = *(const float4*)(in + i8), f1 = *(const float4*)(in + i8 + 4);
    uint4 p;
    p.x = cvth2(f0.x, f0.y); p.y = cvth2(f0.z, f0.w);
    p.z = cvth2(f1.x, f1.y); p.w = cvth2(f1.z, f1.w);
    *(uint4*)(out + i8) = p;
}

// ---------------------------------------------------------------------------
// GEMM1 fused: A = otwH fp16 (glds, dbuf), B = x fp32 (reg-staged, dbuf).
// HEAD-MAJOR remap: zb=blockIdx.x, nn=zb&15, mm=zb>>4 -> XCD = nn%8 for all
// 4 heads of batch nn -> the shared x slab (128i x 1024d fp32) is fetched
// from HBM once per XCD instead of 4x. Outputs use canonical b = nn*4+mm.
// ---------------------------------------------------------------------------
__global__ __launch_bounds__(256)
void gemm1_exp(const unsigned short* __restrict__ otwH, const float* __restrict__ x,
               unsigned short* __restrict__ ekb, float* __restrict__ MiB)
{
    const int zb = blockIdx.x;
    const int nn = zb & 15, mm = zb >> 4;
    const int bt = nn * 4 + mm;               // canonical tile index
    const unsigned short* A = otwH + (long)mm * (OUT_SIZE * IN_DIM);
    const float* B = x + (long)nn * (IN_SIZE * IN_DIM);
    const int n0 = blockIdx.z * 128;          // i-chunk

    __shared__ short As[2][128 * 32];
    __shared__ short Bs[2][128 * 40];
    __shared__ float colmax[2][128];

    const int t = threadIdx.x;
    const int lane = t & 63;
    const int w = t >> 6, wr = w >> 1, wc = w & 1;
    const int lrow = lane >> 2, lce = (lane & 3) * 8;

    auto stage = [&](int buf, int k0) {
        #pragma unroll
        for (int j = 0; j < 2; ++j) {
            const int row0 = (w * 2 + j) * 16;
            glds16(A + (long)(row0 + lrow) * 1024 + k0 + lce, &As[buf][row0 * 32]);
        }
        #pragma unroll
        for (int itr = 0; itr < 2; ++itr) {
            const int idx = itr * 256 + t;
            const int row = idx >> 2, kq = idx & 3;
            const float* s = B + (long)(n0 + row) * 1024 + k0 + kq * 8;
            const float4 f0 = *(const float4*)s, f1 = *(const float4*)(s + 4);
            uint4 p;
            p.x = cvth2(f0.x, f0.y); p.y = cvth2(f0.z, f0.w);
            p.z = cvth2(f1.x, f1.y); p.w = cvth2(f1.z, f1.w);
            *(uint4*)&Bs[buf][row * 40 + kq * 8] = p;
        }
    };

    f32x4 acc[4][4];
    #pragma unroll
    for (int i = 0; i < 4; ++i)
        #pragma unroll
        for (int j = 0; j < 4; ++j) { acc[i][j].x = 0.f; acc[i][j].y = 0.f; acc[i][j].z = 0.f; acc[i][j].w = 0.f; }

    stage(0, 0);
    __syncthreads();
    int cur = 0;

    for (int k0 = 0; k0 < 1024; k0 += 32) {
        if (k0 + 32 < 1024) stage(cur ^ 1, k0 + 32);

        f16x8 af[4], bfr[4];
        #pragma unroll
        for (int mi = 0; mi < 4; ++mi)
            af[mi] = *(const f16x8*)&As[cur][(wr * 64 + mi * 16 + (lane & 15)) * 32 + (lane >> 4) * 8];
        #pragma unroll
        for (int ni = 0; ni < 4; ++ni)
            bfr[ni] = *(const f16x8*)&Bs[cur][(wc * 64 + ni * 16 + (lane & 15)) * 40 + (lane >> 4) * 8];
        #pragma unroll
        for (int mi = 0; mi < 4; ++mi)
            #pragma unroll
            for (int ni = 0; ni < 4; ++ni)
                acc[mi][ni] = __builtin_amdgcn_mfma_f32_16x16x32_f16(af[mi], bfr[ni], acc[mi][ni], 0, 0, 0);
        __syncthreads();
        cur ^= 1;
    }

    float lm[4];
    #pragma unroll
    for (int ni = 0; ni < 4; ++ni) {
        float mx = -INFINITY;
        #pragma unroll
        for (int mi = 0; mi < 4; ++mi)
            #pragma unroll
            for (int j = 0; j < 4; ++j) mx = fmaxf(mx, acc[mi][ni][j]);
        mx *= 10.0f;
        mx = fmaxf(mx, __shfl_xor(mx, 16, 64));
        mx = fmaxf(mx, __shfl_xor(mx, 32, 64));
        lm[ni] = mx;
    }
    if ((lane >> 4) == 0) {
        #pragma unroll
        for (int ni = 0; ni < 4; ++ni) colmax[wr][wc * 64 + ni * 16 + lane] = lm[ni];
    }
    __syncthreads();
    float cm[4];
    #pragma unroll
    for (int ni = 0; ni < 4; ++ni) {
        const int c = wc * 64 + ni * 16 + (lane & 15);
        cm[ni] = fmaxf(colmax[0][c], colmax[1][c]);
    }
    if (wr == 0 && (lane >> 4) == 0) {
        #pragma unroll
        for (int ni = 0; ni < 4; ++ni)
            MiB[(long)bt * 1024 + n0 + wc * 64 + ni * 16 + lane] = cm[ni];
    }
    unsigned short* ekz = ekb + (long)bt * (OUT_SIZE * IN_SIZE);
    #pragma unroll
    for (int mi = 0; mi < 4; ++mi) {
        #pragma unroll
        for (int ni = 0; ni < 4; ++ni) {
            const int col = n0 + wc * 64 + ni * 16 + (lane & 15);
            #pragma unroll
            for (int j = 0; j < 4; ++j) {
                const int row = wr * 64 + mi * 16 + (lane >> 4) * 4 + j;
                ekz[(long)row * 1024 + col] = bf16rne(__expf(fmaf(acc[mi][ni][j], 10.f, -cm[ni])));
            }
        }
    }
}

// ---------------------------------------------------------------------------
__global__ __launch_bounds__(256)
void transpose_cvt(const float* __restrict__ x, unsigned short* __restrict__ xT)
{
    const int n = blockIdx.z, i0 = blockIdx.y * 64, d0 = blockIdx.x * 64;
    const float* xs = x + (long)n * (IN_SIZE * IN_DIM);
    unsigned short* xo = xT + (long)n * (IN_SIZE * IN_DIM);
    __shared__ float tile[64][65];
    const int t = threadIdx.x;
    const int r = t >> 4, c4 = (t & 15) * 4;
    #pragma unroll
    for (int rr = 0; rr < 4; ++rr) {
        const float4 v = *(const float4*)(xs + (long)(i0 + rr * 16 + r) * IN_DIM + d0 + c4);
        *(float4*)&tile[rr * 16 + r][c4] = v;
    }
    __syncthreads();
    #pragma unroll
    for (int rr = 0; rr < 4; ++rr) {
        const int dl = rr * 16 + r;
        ushort4 o;
        o.x = cvth1(tile[c4 + 0][dl]); o.y = cvth1(tile[c4 + 1][dl]);
        o.z = cvth1(tile[c4 + 2][dl]); o.w = cvth1(tile[c4 + 3][dl]);
        *(ushort4*)(xo + (long)(d0 + dl) * IN_SIZE + i0 + c4) = o;
    }
}

// ---------------------------------------------------------------------------
// Sinkhorn v7 (unchanged; fastest measured): 1024 threads, co-located
// siblings on XCD b%8 (grid 64x1x4), 8 barriers/iter, relaxed spin,
// writes T fp16 over the dead ek region.
// ---------------------------------------------------------------------------
__global__ __launch_bounds__(1024)
void sinkhorn_split(unsigned short* __restrict__ ekb,
                    const float* __restrict__ MiB,
                    float* __restrict__ xchg, unsigned int* __restrict__ ctr)
{
    const int b = blockIdx.x;          // tile 0..63 (XCD-aligned)
    const int q = blockIdx.z;          // i-quarter 0..3
    const int t = threadIdx.x;
    const int lane = t & 63, w = t >> 6;

    __shared__ unsigned ekw[128 * 129];
    __shared__ float part_u[8][256];
    __shared__ float part_v[8][128];
    __shared__ float eu_l[256];
    __shared__ float v_s[128], ev_s[128];
    __shared__ float red8[8];
    __shared__ float wg_s;

    {
        const unsigned short* src = ekb + (long)b * 131072 + q * 256;
        #pragma unroll
        for (int j = 0; j < 4; ++j) {
            const int idx = t + 1024 * j;
            const int s = idx >> 5, c8 = (idx & 31) * 8;
            const uint4 p = *(const uint4*)(src + (long)s * 1024 + c8);
            const int bd = s * 129 + (c8 >> 1);
            ekw[bd] = p.x; ekw[bd + 1] = p.y; ekw[bd + 2] = p.z; ekw[bd + 3] = p.w;
        }
    }
    float mi_t = 0.f, u_reg = 0.f, w_t = 0.f;
    if (t < 256) mi_t = MiB[(long)b * 1024 + q * 256 + t];
    if (t < 128) { v_s[t] = 0.f; ev_s[t] = 1.0f; }
    __syncthreads();

    const float A0 = -2.0794415416798357f;
    float vmx = 0.f;

    for (int it = 0; it < MAX_ITER; ++it) {
        {
            const int p = t & 127, sq = t >> 7;
            float s0 = 0.f, s1 = 0.f;
            #pragma unroll
            for (int j = 0; j < 16; ++j) {
                const int s = sq * 16 + j;
                const unsigned e = ekw[s * 129 + p];
                const float evv = ev_s[s];
                s0 = fmaf(__uint_as_float(e << 16),          evv, s0);
                s1 = fmaf(__uint_as_float(e & 0xffff0000u),  evv, s1);
            }
            part_u[sq][2 * p]     = s0;
            part_u[sq][2 * p + 1] = s1;
        }
        __syncthreads();

        if (t < 256) {
            float S = part_u[0][t];
            #pragma unroll
            for (int g = 1; g < 8; ++g) S += part_u[g][t];
            const float un = A0 - u_reg - mi_t - vmx - __logf(S);
            u_reg = un;
            w_t = mi_t + un;
            float wl = w_t;
            #pragma unroll
            for (int m = 1; m < 64; m <<= 1) wl = fmaxf(wl, __shfl_xor(wl, m, 64));
            if (lane == 0) red8[4 + w] = wl;
        }
        __syncthreads();
        const float wmx_l = fmaxf(fmaxf(red8[4], red8[5]), fmaxf(red8[6], red8[7]));
        if (t < 256) eu_l[t] = __expf(w_t - wmx_l);
        __syncthreads();

        {
            const int s = t & 127, g = t >> 7;
            float acc = 0.f;
            #pragma unroll
            for (int j = 0; j < 16; ++j) {
                const int p = 16 * g + j;
                const unsigned e = ekw[s * 129 + p];
                const float2 eup = *(const float2*)&eu_l[2 * p];
                acc = fmaf(__uint_as_float(e << 16),         eup.x, acc);
                acc = fmaf(__uint_as_float(e & 0xffff0000u), eup.y, acc);
            }
            part_v[g][s] = acc;
        }
        __syncthreads();

        float* slot = xchg + ((long)(b * MAX_ITER + it) * 4 + q) * 160;
        if (t < 128) {
            float cp_l = part_v[0][t];
            #pragma unroll
            for (int g = 1; g < 8; ++g) cp_l += part_v[g][t];
            __hip_atomic_store(slot + t, cp_l, __ATOMIC_RELAXED, __HIP_MEMORY_SCOPE_AGENT);
        }
        if (t == 0)
            __hip_atomic_store(slot + 128, wmx_l, __ATOMIC_RELAXED, __HIP_MEMORY_SCOPE_AGENT);
        __syncthreads();
        if (t == 0) {
            unsigned int* c = ctr + b * MAX_ITER + it;
            __hip_atomic_fetch_add(c, 1u, __ATOMIC_RELEASE, __HIP_MEMORY_SCOPE_AGENT);
            while (__hip_atomic_load(c, __ATOMIC_RELAXED, __HIP_MEMORY_SCOPE_AGENT) < 4u) {}
            (void)__hip_atomic_load(c, __ATOMIC_ACQUIRE, __HIP_MEMORY_SCOPE_AGENT);
        }
        __syncthreads();

        if (t < 128) {
            float* base = xchg + (long)(b * MAX_ITER + it) * 4 * 160;
            const float w0 = __hip_atomic_load(base + 0 * 160 + 128, __ATOMIC_RELAXED, __HIP_MEMORY_SCOPE_AGENT);
            const float w1 = __hip_atomic_load(base + 1 * 160 + 128, __ATOMIC_RELAXED, __HIP_MEMORY_SCOPE_AGENT);
            const float w2 = __hip_atomic_load(base + 2 * 160 + 128, __ATOMIC_RELAXED, __HIP_MEMORY_SCOPE_AGENT);
            const float w3 = __hip_atomic_load(base + 3 * 160 + 128, __ATOMIC_RELAXED, __HIP_MEMORY_SCOPE_AGENT);
            const float wg = fmaxf(fmaxf(w0, w1), fmaxf(w2, w3));
            const float c0 = __hip_atomic_load(base + 0 * 160 + t, __ATOMIC_RELAXED, __HIP_MEMORY_SCOPE_AGENT);
            const float c1 = __hip_atomic_load(base + 1 * 160 + t, __ATOMIC_RELAXED, __HIP_MEMORY_SCOPE_AGENT);
            const float c2 = __hip_atomic_load(base + 2 * 160 + t, __ATOMIC_RELAXED, __HIP_MEMORY_SCOPE_AGENT);
            const float c3 = __hip_atomic_load(base + 3 * 160 + t, __ATOMIC_RELAXED, __HIP_MEMORY_SCOPE_AGENT);
            const float cp = c0 * __expf(w0 - wg) + c1 * __expf(w1 - wg)
                           + c2 * __expf(w2 - wg) + c3 * __expf(w3 - wg);
            const float vn = -v_s[t] - wg - __logf(cp);
            v_s[t] = vn;
            if (t == 0) wg_s = wg;
            float xv = vn;
            #pragma unroll
            for (int m = 1; m < 64; m <<= 1) xv = fmaxf(xv, __shfl_xor(xv, m, 64));
            if (lane == 0) red8[w] = xv;
        }
        __syncthreads();
        vmx = fmaxf(red8[0], red8[1]);
        if (t < 128) ev_s[t] = __expf(v_s[t] - vmx);
        __syncthreads();
    }

    const float wg = wg_s;
    if (t < 256) eu_l[t] = __expf(w_t - wg);
    if (t < 128) ev_s[t] = __expf(v_s[t] + wg);
    __syncthreads();
    unsigned short* To = ekb + (long)b * 131072 + q * 256;
    #pragma unroll
    for (int j = 0; j < 16; ++j) {
        const int idx = t + 1024 * j;
        const int s  = idx >> 7;
        const int ip = idx & 127;
        const unsigned e = ekw[s * 129 + ip];
        const float2 eup = *(const float2*)&eu_l[2 * ip];
        const float ec = ev_s[s];
        const float lo = __uint_as_float(e << 16)         * eup.x * ec;
        const float hi = __uint_as_float(e & 0xffff0000u) * eup.y * ec;
        *(unsigned*)(To + (long)s * 1024 + ip * 2) = cvth2(lo, hi);
    }
}

// ---------------------------------------------------------------------------
extern "C" void kernel_launch(void* const* d_in, const int* in_sizes, int n_in,
                              void* d_out, int out_size, void* d_ws, size_t ws_size,
                              hipStream_t stream)
{
    const float* x     = (const float*)d_in[0];   // [16][1024][1024]
    const float* otw   = (const float*)d_in[1];   // [4][128][1024]
    const float* lin_w = (const float*)d_in[2];   // [1024][4096]
    const float* lin_b = (const float*)d_in[3];   // [1024]
    float* out = (float*)d_out;                   // [16][128][1024] fp32 (8 MB)

    // ws (64 MB): [0,32M) xT fp16 (dead after GEMM2 -> split-K partials)
    //             [32M,48M) ek bf16 -> T fp16 in-place; [48M,64M) feat fp16
    unsigned short* xT   = (unsigned short*)d_ws;
    unsigned short* ekb  = xT + 16777216;
    unsigned short* feat = ekb + 8388608;
    float* partial = (float*)d_ws;
    // d_out scratch (fully overwritten by splitk_reduce):
    //   Mi [64][1024] @0 ; xchg @131072 ; ctr @655360 ; otwH fp16 @786432
    float* MiB  = (float*)d_out;
    float* xchg = MiB + 131072;
    unsigned int* ctrB = (unsigned int*)(MiB + 655360);
    unsigned short* otwH = (unsigned short*)(MiB + 786432);

    hipMemsetAsync(ctrB, 0, 64 * MAX_ITER * sizeof(unsigned int), stream);

    // -1) otw -> fp16 (tiny)
    cvt_f16<<<dim3(256), 256, 0, stream>>>(otw, otwH);

    // 1) fused K-GEMM + colmax + exp: head-major remap -> x slab 1x HBM fetch
    gemm1_exp<<<dim3(64, 1, 8), 256, 0, stream>>>(otwH, x, ekb, MiB);

    // 0) x -> xT fp16
    transpose_cvt<<<dim3(16, 16, NB), 256, 0, stream>>>(x, xT);

    // 2) Sinkhorn v7 -> T fp16 over ek
    sinkhorn_split<<<dim3(64, 1, 4), 1024, 0, stream>>>(ekb, MiB, xchg, ctrB);

    // 3) feat = T . xT^T (both fp16 glds dbuf, HMAP: xT slab 1x per XCD)
    mfma_gemm<false, 1, 4, true, true><<<dim3(64, 1, 8), 256, 0, stream>>>(
        ekb, xT, nullptr, feat,
        1024, 1024, 1024, 1024, 4,
        0, 131072, 1048576, 0, 0, 131072, 1.0f);

    // 4) split-K x4 GEMM3: A glds dbuf, B fp32 reg-staged
    mfma_gemm<true, 4, 2, false, false><<<dim3(16, 1, 64), 256, 0, stream>>>(
        feat, lin_w, nullptr, partial,
        1024, 1024, 4096, 1024, 16,
        131072, 524288, 1024, 0, 2097152, 131072, 1.0f);

    // 5) out = relu(sum_ks partial + bias)
    splitk_reduce<<<dim3(2048), 256, 0, stream>>>(partial, lin_b, out);
}

// Round 20
// 188.533 us; speedup vs baseline: 1.1192x; 1.0152x over previous
//
#include <hip/hip_runtime.h>
#include <math.h>

#define EPSV 0.1f
#define MAX_ITER 10
constexpr int NB       = 16;
constexpr int IN_SIZE  = 1024;
constexpr int IN_DIM   = 1024;
constexpr int HEADS    = 4;
constexpr int OUT_SIZE = 128;
constexpr int OUT_DIM  = 1024;

typedef __attribute__((ext_vector_type(8))) _Float16 f16x8;
typedef __attribute__((ext_vector_type(4))) float f32x4;

__device__ __forceinline__ unsigned cvth2(float lo, float hi) {
    _Float16 a = (_Float16)lo, b = (_Float16)hi;
    unsigned short ua = *(unsigned short*)&a, ub = *(unsigned short*)&b;
    return (unsigned)ua | ((unsigned)ub << 16);
}
__device__ __forceinline__ unsigned short cvth1(float f) {
    _Float16 a = (_Float16)f;
    return *(unsigned short*)&a;
}
__device__ __forceinline__ unsigned short bf16rne(float f) {
    unsigned a = __float_as_uint(f);
    return (unsigned short)((a + 0x7fffu + ((a >> 16) & 1u)) >> 16);
}
// async global->LDS, 16 B per lane: HW writes lane l at ldsbase + l*16.
__device__ __forceinline__ void glds16(const void* g, void* l) {
    __builtin_amdgcn_global_load_lds(
        (const __attribute__((address_space(1))) unsigned int*)g,
        (__attribute__((address_space(3))) unsigned int*)l, 16, 0, 0);
}

// ---------------------------------------------------------------------------
// MFMA fp16 GEMM, M fixed 128, double-buffered. A fp16 glds (linear LDS
// [rows][32]); B fp16 glds or fp32 reg-staged (padded 40).
// CMODE: 1 = fp16 store, 2 = f32+bias+relu
// HMAP : head-major tile remap (z&15=n, z>>4=m, b=n*4+m) -> all 4 heads of
//        batch n on XCD n%8: shared B slab fetched once per XCD.
// ---------------------------------------------------------------------------
template<bool B_F32, int CMODE, int NF, bool SWAP, bool HMAP>
__global__ __launch_bounds__(256)
void mfma_gemm(const void* __restrict__ Ap, const void* __restrict__ Bp,
               const float* __restrict__ bias, void* __restrict__ Cp,
               int K, int lda, int ldb, int ldc, int div,
               long AsN, long AsM, long BsN, long BsM, long CsN, long CsM,
               float alpha)
{
    constexpr int BN   = NF * 32;
    constexpr int BSTR = B_F32 ? 40 : 32;   // B LDS row stride (elems)
    const int z  = SWAP ? blockIdx.x : blockIdx.z;
    const int n0 = (SWAP ? blockIdx.z : blockIdx.x) * BN;
    long aoff, boff, coff;
    if (HMAP) {
        const int nn = z & 15, mm = z >> 4, bt = nn * 4 + mm;
        aoff = (long)bt * AsM; boff = (long)nn * BsN; coff = (long)bt * CsM;
    } else {
        aoff = (long)(z / div) * AsN + (long)(z % div) * AsM;
        boff = (long)(z / div) * BsN + (long)(z % div) * BsM;
        coff = (long)(z / div) * CsN + (long)(z % div) * CsM;
    }

    __shared__ short As[2][128 * 32];
    __shared__ short Bs[2][BN * BSTR];

    const int t = threadIdx.x;
    const int lane = t & 63;
    const int w = t >> 6, wr = w >> 1, wc = w & 1;
    const int lrow = lane >> 2, lce = (lane & 3) * 8;   // glds lane mapping

    auto stage = [&](int buf, int k0) {
        const long abase = aoff + k0;
        const long bbase = boff + k0;
        #pragma unroll
        for (int j = 0; j < 2; ++j) {
            const int row0 = (w * 2 + j) * 16;
            glds16((const short*)Ap + abase + (long)(row0 + lrow) * lda + lce,
                   &As[buf][row0 * 32]);
        }
        if (B_F32) {
            #pragma unroll
            for (int itr = 0; itr < BN / 64; ++itr) {
                const int idx = itr * 256 + t;
                const int row = idx >> 2, kq = idx & 3;
                const float* s = (const float*)Bp + bbase + (long)(n0 + row) * ldb + kq * 8;
                const float4 f0 = *(const float4*)s, f1 = *(const float4*)(s + 4);
                uint4 p;
                p.x = cvth2(f0.x, f0.y); p.y = cvth2(f0.z, f0.w);
                p.z = cvth2(f1.x, f1.y); p.w = cvth2(f1.z, f1.w);
                *(uint4*)&Bs[buf][row * BSTR + kq * 8] = p;
            }
        } else {
            #pragma unroll
            for (int j = 0; j < BN / 64; ++j) {
                const int row0 = (w * (BN / 64) + j) * 16;
                glds16((const short*)Bp + bbase + (long)(n0 + row0 + lrow) * ldb + lce,
                       &Bs[buf][row0 * 32]);
            }
        }
    };

    f32x4 acc[4][NF];
    #pragma unroll
    for (int i = 0; i < 4; ++i)
        #pragma unroll
        for (int j = 0; j < NF; ++j) { acc[i][j].x = 0.f; acc[i][j].y = 0.f; acc[i][j].z = 0.f; acc[i][j].w = 0.f; }

    stage(0, 0);
    __syncthreads();
    int cur = 0;

    for (int k0 = 0; k0 < K; k0 += 32) {
        if (k0 + 32 < K) stage(cur ^ 1, k0 + 32);

        f16x8 af[4], bfr[NF];
        #pragma unroll
        for (int mi = 0; mi < 4; ++mi)
            af[mi] = *(const f16x8*)&As[cur][(wr * 64 + mi * 16 + (lane & 15)) * 32 + (lane >> 4) * 8];
        #pragma unroll
        for (int ni = 0; ni < NF; ++ni)
            bfr[ni] = *(const f16x8*)&Bs[cur][(wc * (BN / 2) + ni * 16 + (lane & 15)) * BSTR + (lane >> 4) * 8];
        #pragma unroll
        for (int mi = 0; mi < 4; ++mi)
            #pragma unroll
            for (int ni = 0; ni < NF; ++ni)
                acc[mi][ni] = __builtin_amdgcn_mfma_f32_16x16x32_f16(af[mi], bfr[ni], acc[mi][ni], 0, 0, 0);
        __syncthreads();
        cur ^= 1;
    }

    #pragma unroll
    for (int mi = 0; mi < 4; ++mi) {
        #pragma unroll
        for (int ni = 0; ni < NF; ++ni) {
            #pragma unroll
            for (int j = 0; j < 4; ++j) {
                const int row = wr * 64 + mi * 16 + (lane >> 4) * 4 + j;
                const int col = n0 + wc * (BN / 2) + ni * 16 + (lane & 15);
                float v = acc[mi][ni][j] * alpha;
                if (CMODE == 2) { v += bias[col]; v = fmaxf(v, 0.f); }
                if (CMODE == 2) ((float*)Cp)[coff + (long)row * ldc + col] = v;
                else ((unsigned short*)Cp)[coff + (long)row * ldc + col] = cvth1(v);
            }
        }
    }
}

// ---------------------------------------------------------------------------
// split-K reduce (fp16 partials): out = relu(sum_ks p[ks] + bias), 8/thread.
// ---------------------------------------------------------------------------
__global__ __launch_bounds__(256)
void splitk_reduce(const unsigned short* __restrict__ part,
                   const float* __restrict__ bias, float* __restrict__ out)
{
    const long idx = ((long)blockIdx.x * 256 + threadIdx.x) * 8;
    const int o = (int)(idx & 1023);
    const f16x8 p0 = *(const f16x8*)(part + idx);
    const f16x8 p1 = *(const f16x8*)(part + 2097152 + idx);
    const f16x8 p2 = *(const f16x8*)(part + 2 * 2097152 + idx);
    const f16x8 p3 = *(const f16x8*)(part + 3 * 2097152 + idx);
    const float4 b0 = *(const float4*)(bias + o);
    const float4 b1 = *(const float4*)(bias + o + 4);
    float r[8];
    #pragma unroll
    for (int j = 0; j < 8; ++j) {
        const float bv = j < 4 ? (&b0.x)[j] : (&b1.x)[j - 4];
        r[j] = fmaxf((float)p0[j] + (float)p1[j] + (float)p2[j] + (float)p3[j] + bv, 0.f);
    }
    *(float4*)(out + idx)     = *(float4*)&r[0];
    *(float4*)(out + idx + 4) = *(float4*)&r[4];
}

// ---------------------------------------------------------------------------
__global__ __launch_bounds__(256)
void cvt_f16(const float* __restrict__ in, unsigned short* __restrict__ out)
{
    const long i8 = ((long)blockIdx.x * 256 + threadIdx.x) * 8;
    const float4 f0 = *(const float4*)(in + i8), f1 = *(const float4*)(in + i8 + 4);
    uint4 p;
    p.x = cvth2(f0.x, f0.y); p.y = cvth2(f0.z, f0.w);
    p.z = cvth2(f1.x, f1.y); p.w = cvth2(f1.z, f1.w);
    *(uint4*)(out + i8) = p;
}

// ---------------------------------------------------------------------------
// GEMM1 fused (R18 version): A = otwH fp16 glds dbuf, B = x fp32 reg-staged
// dbuf, head-major remap, colmax -> Mi, ek = bf16(exp(K-Mi)).
// ---------------------------------------------------------------------------
__global__ __launch_bounds__(256)
void gemm1_exp(const unsigned short* __restrict__ otwH, const float* __restrict__ x,
               unsigned short* __restrict__ ekb, float* __restrict__ MiB)
{
    const int zb = blockIdx.x;
    const int nn = zb & 15, mm = zb >> 4;
    const int bt = nn * 4 + mm;               // canonical tile index
    const unsigned short* A = otwH + (long)mm * (OUT_SIZE * IN_DIM);
    const float* B = x + (long)nn * (IN_SIZE * IN_DIM);
    const int n0 = blockIdx.z * 128;          // i-chunk

    __shared__ short As[2][128 * 32];
    __shared__ short Bs[2][128 * 40];
    __shared__ float colmax[2][128];

    const int t = threadIdx.x;
    const int lane = t & 63;
    const int w = t >> 6, wr = w >> 1, wc = w & 1;
    const int lrow = lane >> 2, lce = (lane & 3) * 8;

    auto stage = [&](int buf, int k0) {
        #pragma unroll
        for (int j = 0; j < 2; ++j) {
            const int row0 = (w * 2 + j) * 16;
            glds16(A + (long)(row0 + lrow) * 1024 + k0 + lce, &As[buf][row0 * 32]);
        }
        #pragma unroll
        for (int itr = 0; itr < 2; ++itr) {
            const int idx = itr * 256 + t;
            const int row = idx >> 2, kq = idx & 3;
            const float* s = B + (long)(n0 + row) * 1024 + k0 + kq * 8;
            const float4 f0 = *(const float4*)s, f1 = *(const float4*)(s + 4);
            uint4 p;
            p.x = cvth2(f0.x, f0.y); p.y = cvth2(f0.z, f0.w);
            p.z = cvth2(f1.x, f1.y); p.w = cvth2(f1.z, f1.w);
            *(uint4*)&Bs[buf][row * 40 + kq * 8] = p;
        }
    };

    f32x4 acc[4][4];
    #pragma unroll
    for (int i = 0; i < 4; ++i)
        #pragma unroll
        for (int j = 0; j < 4; ++j) { acc[i][j].x = 0.f; acc[i][j].y = 0.f; acc[i][j].z = 0.f; acc[i][j].w = 0.f; }

    stage(0, 0);
    __syncthreads();
    int cur = 0;

    for (int k0 = 0; k0 < 1024; k0 += 32) {
        if (k0 + 32 < 1024) stage(cur ^ 1, k0 + 32);

        f16x8 af[4], bfr[4];
        #pragma unroll
        for (int mi = 0; mi < 4; ++mi)
            af[mi] = *(const f16x8*)&As[cur][(wr * 64 + mi * 16 + (lane & 15)) * 32 + (lane >> 4) * 8];
        #pragma unroll
        for (int ni = 0; ni < 4; ++ni)
            bfr[ni] = *(const f16x8*)&Bs[cur][(wc * 64 + ni * 16 + (lane & 15)) * 40 + (lane >> 4) * 8];
        #pragma unroll
        for (int mi = 0; mi < 4; ++mi)
            #pragma unroll
            for (int ni = 0; ni < 4; ++ni)
                acc[mi][ni] = __builtin_amdgcn_mfma_f32_16x16x32_f16(af[mi], bfr[ni], acc[mi][ni], 0, 0, 0);
        __syncthreads();
        cur ^= 1;
    }

    float lm[4];
    #pragma unroll
    for (int ni = 0; ni < 4; ++ni) {
        float mx = -INFINITY;
        #pragma unroll
        for (int mi = 0; mi < 4; ++mi)
            #pragma unroll
            for (int j = 0; j < 4; ++j) mx = fmaxf(mx, acc[mi][ni][j]);
        mx *= 10.0f;
        mx = fmaxf(mx, __shfl_xor(mx, 16, 64));
        mx = fmaxf(mx, __shfl_xor(mx, 32, 64));
        lm[ni] = mx;
    }
    if ((lane >> 4) == 0) {
        #pragma unroll
        for (int ni = 0; ni < 4; ++ni) colmax[wr][wc * 64 + ni * 16 + lane] = lm[ni];
    }
    __syncthreads();
    float cm[4];
    #pragma unroll
    for (int ni = 0; ni < 4; ++ni) {
        const int c = wc * 64 + ni * 16 + (lane & 15);
        cm[ni] = fmaxf(colmax[0][c], colmax[1][c]);
    }
    if (wr == 0 && (lane >> 4) == 0) {
        #pragma unroll
        for (int ni = 0; ni < 4; ++ni)
            MiB[(long)bt * 1024 + n0 + wc * 64 + ni * 16 + lane] = cm[ni];
    }
    unsigned short* ekz = ekb + (long)bt * (OUT_SIZE * IN_SIZE);
    #pragma unroll
    for (int mi = 0; mi < 4; ++mi) {
        #pragma unroll
        for (int ni = 0; ni < 4; ++ni) {
            const int col = n0 + wc * 64 + ni * 16 + (lane & 15);
            #pragma unroll
            for (int j = 0; j < 4; ++j) {
                const int row = wr * 64 + mi * 16 + (lane >> 4) * 4 + j;
                ekz[(long)row * 1024 + col] = bf16rne(__expf(fmaf(acc[mi][ni][j], 10.f, -cm[ni])));
            }
        }
    }
}

// ---------------------------------------------------------------------------
__global__ __launch_bounds__(256)
void transpose_cvt(const float* __restrict__ x, unsigned short* __restrict__ xT)
{
    const int n = blockIdx.z, i0 = blockIdx.y * 64, d0 = blockIdx.x * 64;
    const float* xs = x + (long)n * (IN_SIZE * IN_DIM);
    unsigned short* xo = xT + (long)n * (IN_SIZE * IN_DIM);
    __shared__ float tile[64][65];
    const int t = threadIdx.x;
    const int r = t >> 4, c4 = (t & 15) * 4;
    #pragma unroll
    for (int rr = 0; rr < 4; ++rr) {
        const float4 v = *(const float4*)(xs + (long)(i0 + rr * 16 + r) * IN_DIM + d0 + c4);
        *(float4*)&tile[rr * 16 + r][c4] = v;
    }
    __syncthreads();
    #pragma unroll
    for (int rr = 0; rr < 4; ++rr) {
        const int dl = rr * 16 + r;
        ushort4 o;
        o.x = cvth1(tile[c4 + 0][dl]); o.y = cvth1(tile[c4 + 1][dl]);
        o.z = cvth1(tile[c4 + 2][dl]); o.w = cvth1(tile[c4 + 3][dl]);
        *(ushort4*)(xo + (long)(d0 + dl) * IN_SIZE + i0 + c4) = o;
    }
}

// ---------------------------------------------------------------------------
// Sinkhorn v7 (unchanged; fastest measured).
// ---------------------------------------------------------------------------
__global__ __launch_bounds__(1024)
void sinkhorn_split(unsigned short* __restrict__ ekb,
                    const float* __restrict__ MiB,
                    float* __restrict__ xchg, unsigned int* __restrict__ ctr)
{
    const int b = blockIdx.x;          // tile 0..63 (XCD-aligned)
    const int q = blockIdx.z;          // i-quarter 0..3
    const int t = threadIdx.x;
    const int lane = t & 63, w = t >> 6;

    __shared__ unsigned ekw[128 * 129];
    __shared__ float part_u[8][256];
    __shared__ float part_v[8][128];
    __shared__ float eu_l[256];
    __shared__ float v_s[128], ev_s[128];
    __shared__ float red8[8];
    __shared__ float wg_s;

    {
        const unsigned short* src = ekb + (long)b * 131072 + q * 256;
        #pragma unroll
        for (int j = 0; j < 4; ++j) {
            const int idx = t + 1024 * j;
            const int s = idx >> 5, c8 = (idx & 31) * 8;
            const uint4 p = *(const uint4*)(src + (long)s * 1024 + c8);
            const int bd = s * 129 + (c8 >> 1);
            ekw[bd] = p.x; ekw[bd + 1] = p.y; ekw[bd + 2] = p.z; ekw[bd + 3] = p.w;
        }
    }
    float mi_t = 0.f, u_reg = 0.f, w_t = 0.f;
    if (t < 256) mi_t = MiB[(long)b * 1024 + q * 256 + t];
    if (t < 128) { v_s[t] = 0.f; ev_s[t] = 1.0f; }
    __syncthreads();

    const float A0 = -2.0794415416798357f;
    float vmx = 0.f;

    for (int it = 0; it < MAX_ITER; ++it) {
        {
            const int p = t & 127, sq = t >> 7;
            float s0 = 0.f, s1 = 0.f;
            #pragma unroll
            for (int j = 0; j < 16; ++j) {
                const int s = sq * 16 + j;
                const unsigned e = ekw[s * 129 + p];
                const float evv = ev_s[s];
                s0 = fmaf(__uint_as_float(e << 16),          evv, s0);
                s1 = fmaf(__uint_as_float(e & 0xffff0000u),  evv, s1);
            }
            part_u[sq][2 * p]     = s0;
            part_u[sq][2 * p + 1] = s1;
        }
        __syncthreads();

        if (t < 256) {
            float S = part_u[0][t];
            #pragma unroll
            for (int g = 1; g < 8; ++g) S += part_u[g][t];
            const float un = A0 - u_reg - mi_t - vmx - __logf(S);
            u_reg = un;
            w_t = mi_t + un;
            float wl = w_t;
            #pragma unroll
            for (int m = 1; m < 64; m <<= 1) wl = fmaxf(wl, __shfl_xor(wl, m, 64));
            if (lane == 0) red8[4 + w] = wl;
        }
        __syncthreads();
        const float wmx_l = fmaxf(fmaxf(red8[4], red8[5]), fmaxf(red8[6], red8[7]));
        if (t < 256) eu_l[t] = __expf(w_t - wmx_l);
        __syncthreads();

        {
            const int s = t & 127, g = t >> 7;
            float acc = 0.f;
            #pragma unroll
            for (int j = 0; j < 16; ++j) {
                const int p = 16 * g + j;
                const unsigned e = ekw[s * 129 + p];
                const float2 eup = *(const float2*)&eu_l[2 * p];
                acc = fmaf(__uint_as_float(e << 16),         eup.x, acc);
                acc = fmaf(__uint_as_float(e & 0xffff0000u), eup.y, acc);
            }
            part_v[g][s] = acc;
        }
        __syncthreads();

        float* slot = xchg + ((long)(b * MAX_ITER + it) * 4 + q) * 160;
        if (t < 128) {
            float cp_l = part_v[0][t];
            #pragma unroll
            for (int g = 1; g < 8; ++g) cp_l += part_v[g][t];
            __hip_atomic_store(slot + t, cp_l, __ATOMIC_RELAXED, __HIP_MEMORY_SCOPE_AGENT);
        }
        if (t == 0)
            __hip_atomic_store(slot + 128, wmx_l, __ATOMIC_RELAXED, __HIP_MEMORY_SCOPE_AGENT);
        __syncthreads();
        if (t == 0) {
            unsigned int* c = ctr + b * MAX_ITER + it;
            __hip_atomic_fetch_add(c, 1u, __ATOMIC_RELEASE, __HIP_MEMORY_SCOPE_AGENT);
            while (__hip_atomic_load(c, __ATOMIC_RELAXED, __HIP_MEMORY_SCOPE_AGENT) < 4u) {}
            (void)__hip_atomic_load(c, __ATOMIC_ACQUIRE, __HIP_MEMORY_SCOPE_AGENT);
        }
        __syncthreads();

        if (t < 128) {
            float* base = xchg + (long)(b * MAX_ITER + it) * 4 * 160;
            const float w0 = __hip_atomic_load(base + 0 * 160 + 128, __ATOMIC_RELAXED, __HIP_MEMORY_SCOPE_AGENT);
            const float w1 = __hip_atomic_load(base + 1 * 160 + 128, __ATOMIC_RELAXED, __HIP_MEMORY_SCOPE_AGENT);
            const float w2 = __hip_atomic_load(base + 2 * 160 + 128, __ATOMIC_RELAXED, __HIP_MEMORY_SCOPE_AGENT);
            const float w3 = __hip_atomic_load(base + 3 * 160 + 128, __ATOMIC_RELAXED, __HIP_MEMORY_SCOPE_AGENT);
            const float wg = fmaxf(fmaxf(w0, w1), fmaxf(w2, w3));
            const float c0 = __hip_atomic_load(base + 0 * 160 + t, __ATOMIC_RELAXED, __HIP_MEMORY_SCOPE_AGENT);
            const float c1 = __hip_atomic_load(base + 1 * 160 + t, __ATOMIC_RELAXED, __HIP_MEMORY_SCOPE_AGENT);
            const float c2 = __hip_atomic_load(base + 2 * 160 + t, __ATOMIC_RELAXED, __HIP_MEMORY_SCOPE_AGENT);
            const float c3 = __hip_atomic_load(base + 3 * 160 + t, __ATOMIC_RELAXED, __HIP_MEMORY_SCOPE_AGENT);
            const float cp = c0 * __expf(w0 - wg) + c1 * __expf(w1 - wg)
                           + c2 * __expf(w2 - wg) + c3 * __expf(w3 - wg);
            const float vn = -v_s[t] - wg - __logf(cp);
            v_s[t] = vn;
            if (t == 0) wg_s = wg;
            float xv = vn;
            #pragma unroll
            for (int m = 1; m < 64; m <<= 1) xv = fmaxf(xv, __shfl_xor(xv, m, 64));
            if (lane == 0) red8[w] = xv;
        }
        __syncthreads();
        vmx = fmaxf(red8[0], red8[1]);
        if (t < 128) ev_s[t] = __expf(v_s[t] - vmx);
        __syncthreads();
    }

    const float wg = wg_s;
    if (t < 256) eu_l[t] = __expf(w_t - wg);
    if (t < 128) ev_s[t] = __expf(v_s[t] + wg);
    __syncthreads();
    unsigned short* To = ekb + (long)b * 131072 + q * 256;
    #pragma unroll
    for (int j = 0; j < 16; ++j) {
        const int idx = t + 1024 * j;
        const int s  = idx >> 7;
        const int ip = idx & 127;
        const unsigned e = ekw[s * 129 + ip];
        const float2 eup = *(const float2*)&eu_l[2 * ip];
        const float ec = ev_s[s];
        const float lo = __uint_as_float(e << 16)         * eup.x * ec;
        const float hi = __uint_as_float(e & 0xffff0000u) * eup.y * ec;
        *(unsigned*)(To + (long)s * 1024 + ip * 2) = cvth2(lo, hi);
    }
}

// ---------------------------------------------------------------------------
extern "C" void kernel_launch(void* const* d_in, const int* in_sizes, int n_in,
                              void* d_out, int out_size, void* d_ws, size_t ws_size,
                              hipStream_t stream)
{
    const float* x     = (const float*)d_in[0];   // [16][1024][1024]
    const float* otw   = (const float*)d_in[1];   // [4][128][1024]
    const float* lin_w = (const float*)d_in[2];   // [1024][4096]
    const float* lin_b = (const float*)d_in[3];   // [1024]
    float* out = (float*)d_out;                   // [16][128][1024] fp32 (8 MB)

    // ws (64 MB): [0,32M) xT fp16 (dead after GEMM2 -> fp16 split-K partials,
    //             16 MB of the region); [32M,48M) ek bf16 -> T fp16 in-place;
    //             [48M,64M) feat fp16
    unsigned short* xT   = (unsigned short*)d_ws;
    unsigned short* ekb  = xT + 16777216;
    unsigned short* feat = ekb + 8388608;
    unsigned short* partial = (unsigned short*)d_ws;  // [4][16][128][1024] fp16
    // d_out scratch (fully overwritten by splitk_reduce):
    //   Mi [64][1024] @0 ; xchg @131072 ; ctr @655360 ; otwH fp16 @786432
    float* MiB  = (float*)d_out;
    float* xchg = MiB + 131072;
    unsigned int* ctrB = (unsigned int*)(MiB + 655360);
    unsigned short* otwH = (unsigned short*)(MiB + 786432);

    hipMemsetAsync(ctrB, 0, 64 * MAX_ITER * sizeof(unsigned int), stream);

    // -1) otw -> fp16 (tiny)
    cvt_f16<<<dim3(256), 256, 0, stream>>>(otw, otwH);

    // 1) fused K-GEMM + colmax + exp: head-major remap
    gemm1_exp<<<dim3(64, 1, 8), 256, 0, stream>>>(otwH, x, ekb, MiB);

    // 0) x -> xT fp16
    transpose_cvt<<<dim3(16, 16, NB), 256, 0, stream>>>(x, xT);

    // 2) Sinkhorn v7 -> T fp16 over ek
    sinkhorn_split<<<dim3(64, 1, 4), 1024, 0, stream>>>(ekb, MiB, xchg, ctrB);

    // 3) feat = T . xT^T: NF=2, grid (64,1,16) = 4 blocks/CU, HMAP
    mfma_gemm<false, 1, 2, true, true><<<dim3(64, 1, 16), 256, 0, stream>>>(
        ekb, xT, nullptr, feat,
        1024, 1024, 1024, 1024, 4,
        0, 131072, 1048576, 0, 0, 131072, 1.0f);

    // 4) split-K x4 GEMM3 -> fp16 partials (CMODE 1)
    mfma_gemm<true, 1, 2, false, false><<<dim3(16, 1, 64), 256, 0, stream>>>(
        feat, lin_w, nullptr, partial,
        1024, 1024, 4096, 1024, 16,
        131072, 524288, 1024, 0, 2097152, 131072, 1.0f);

    // 5) out = relu(sum_ks partial + bias)
    splitk_reduce<<<dim3(1024), 256, 0, stream>>>(partial, lin_b, out);
}